// Round 5
// baseline (3119.752 us; speedup 1.0000x reference)
//
#include <hip/hip_runtime.h>
#include <hip/hip_bf16.h>
#include <math.h>

// ============================================================================
// ResponseFilter — round 7: counted-vmcnt GEMM K-loop (T4 proper).
//
// Round-6 post-mortem: 256^2 tile landed but GEMM only ~580 TF. Cause: the
// per-K-tile __syncthreads drains vmcnt(0) right after the last staging slice
// was issued (~150 cy cover vs 200-900 cy latency) — the m218-documented
// "8-phase-with-drain0 == 1-phase" failure. Fix = the proven counted pattern:
//   prologue: STAGE(t0), STAGE(t1), vmcnt(8), barrier
//   loop kt : compute(buf kt) -> s_barrier -> STAGE(kt+2 into freed buf)
//             -> s_waitcnt vmcnt(8)  [waits tile kt+1 only; kt+2 in flight]
//             -> s_barrier
//   vmcnt never drains to 0 mid-loop; every load gets a full compute-tile
//   (~614 cy) of cover. sched_barrier(0) pins all asm waits/barriers (r18).
// Everything else unchanged from round 6 (passed, absmax 0).
// ============================================================================

#define B_  16
#define T_  32
#define L_  64
#define D_  768
#define H_  12
#define F_  2048
#define ZR_ 100
#define ZP_ 128
#define NP_ 512
#define EPS_ 1e-5f

// meta int offsets (d_ws as int*)
#define MI_NTOT  0
#define MI_NRESP 8
#define MI_OFF   32
#define MI_BIDX  64
#define MI_TIDX  576
#define MI_NODE  1088

// ws float offsets
#define WS_BIAS2 2048
#define WS_EMEAN 34816
#define WS_S     428032
#define WS_WST   428544    // bf16 weight stage, 1,769,472 ushorts (3.54 MB)
#define WS_BIG   1313280   // bf16 QKV/hidden region; fp32 Z overlay

// d_out float offsets (flat tuple: oh[512], ext_mask[32768], n_ext_adv[1],
// new_tree_lens[16], new_emb[25165824], new_msk[32768])
#define OUT_OH   0
#define OUT_EXT  512
#define OUT_NEA  33280
#define OUT_NTL  33281
#define OUT_NEMB 33297
#define OUT_NMSK 25199121
#define OUT_XSCR 33300   // bf16 X scratch (16B aligned), 32768*768 ushorts

typedef __attribute__((ext_vector_type(8))) short short8;
typedef __attribute__((ext_vector_type(4))) float f32x4;

__device__ inline float bf2f(unsigned s) {
  return __uint_as_float((s & 0xffffu) << 16);
}
__device__ inline unsigned short f2bf(float x) {
  unsigned u = __float_as_uint(x);
  u += 0x7fffu + ((u >> 16) & 1u);      // round-to-nearest-even
  return (unsigned short)(u >> 16);
}
__device__ inline unsigned pack2(float a, float b) {
  return (unsigned)f2bf(a) | ((unsigned)f2bf(b) << 16);
}

// ---------------------------------------------------------------------------
__global__ void meta_kernel(const int* __restrict__ tl, int* __restrict__ mi) {
  if (threadIdx.x != 0) return;
  int off = 0;
  for (int b = 0; b < B_; b++) {
    int nr = tl[b] - 1;
    mi[MI_NRESP + b] = nr;
    mi[MI_OFF + b] = off;
    off += nr;
  }
  mi[MI_NTOT] = off;
  for (int j = 0; j < NP_; j++) {
    int b = -1, t = 0;
    if (j < off) {
      b = 0;
      while (b + 1 < B_ && j >= mi[MI_OFF + b + 1]) b++;
      t = j - mi[MI_OFF + b] + 1;
    }
    mi[MI_BIDX + j] = b;
    mi[MI_TIDX + j] = t;
  }
}

// ---------------------------------------------------------------------------
// fp32 -> bf16 weight conversion (n multiple of 1024)
__global__ __launch_bounds__(256) void w2bf_kernel(const float* __restrict__ W,
                                                   unsigned short* __restrict__ o) {
  const int i = (blockIdx.x * 256 + threadIdx.x) * 4;
  float4 v = *(const float4*)(W + i);
  uint2 pk; pk.x = pack2(v.x, v.y); pk.y = pack2(v.z, v.w);
  *(uint2*)(o + i) = pk;
}

// ---------------------------------------------------------------------------
// X[j,l,:] bf16 = reply embedding (zero for padded j); bias2 = mask or -1e30
__global__ __launch_bounds__(192) void gather_kernel(
    const float* __restrict__ emb, const float* __restrict__ am,
    const int* __restrict__ mi, unsigned short* __restrict__ X,
    float* __restrict__ bias2) {
  const int blk = blockIdx.x;          // j*64 + l
  const int j = blk >> 6, l = blk & 63;
  const int ntot = mi[MI_NTOT];
  const int t = threadIdx.x;
  float4 v = make_float4(0.f, 0.f, 0.f, 0.f);
  if (j < ntot) {
    const int b = mi[MI_BIDX + j], tt = mi[MI_TIDX + j];
    v = ((const float4*)(emb + (size_t)((b * T_ + tt) * L_ + l) * D_))[t];
    if (t == 0) bias2[blk] = am[(b * T_ + tt) * L_ + l];
  } else {
    if (t == 0) bias2[blk] = -1e30f;
  }
  uint2 pk; pk.x = pack2(v.x, v.y); pk.y = pack2(v.z, v.w);
  *(uint2*)(X + (size_t)blk * D_ + t * 4) = pk;
}

// ---------------------------------------------------------------------------
// zero QKV rows >= ntot*64 in BIG (once per launch): attention reads K/V for
// all 512 padded responses; rows beyond the last GEMM tile must be finite.
__global__ __launch_bounds__(256) void zerotail_kernel(const int* __restrict__ mi,
                                                       unsigned short* __restrict__ BIG) {
  const int row = blockIdx.x;                 // 0 .. 32767
  if (row < mi[MI_NTOT] * 64) return;
  uint4 z = make_uint4(0u, 0u, 0u, 0u);
  uint4* p = (uint4*)(BIG + (size_t)row * 2304);   // 2304 ushorts = 288 uint4
  for (int c = threadIdx.x; c < 288; c += 256) p[c] = z;
}

// ---------------------------------------------------------------------------
__global__ __launch_bounds__(256) void emean_kernel(const unsigned short* __restrict__ X,
                                                    float* __restrict__ em) {
  const int j = blockIdx.x;
  int d = threadIdx.x;
  for (int c = 0; c < 3; c++, d += 256) {
    const unsigned short* p = X + (size_t)j * L_ * D_ + d;
    float s = 0.f;
    for (int l = 0; l < L_; l++) s += bf2f(p[l * D_]);
    em[j * D_ + d] = s * (1.f / 64.f);
  }
}

// ---------------------------------------------------------------------------
__device__ inline float blockSum256(float v, float* red) {
  #pragma unroll
  for (int o = 32; o > 0; o >>= 1) v += __shfl_down(v, o);
  const int lane = threadIdx.x & 63, wid = threadIdx.x >> 6;
  __syncthreads();
  if (lane == 0) red[wid] = v;
  __syncthreads();
  return red[0] + red[1] + red[2] + red[3];
}

// in-place LN (bf16 storage, fp32 stats); skips padded rows
__global__ __launch_bounds__(256) void ln_kernel(unsigned short* __restrict__ X,
                                                 const float* __restrict__ g,
                                                 const float* __restrict__ bb,
                                                 const int* __restrict__ mi) {
  const int row = blockIdx.x;
  if (row >= mi[MI_NTOT] * L_) return;
  unsigned short* p = X + (size_t)row * D_;
  const int t = threadIdx.x;
  __shared__ float red[4];
  float v0 = bf2f(p[t]), v1 = bf2f(p[t + 256]), v2 = bf2f(p[t + 512]);
  float s = blockSum256(v0 + v1 + v2, red);
  float m = s * (1.f / 768.f);
  float d0 = v0 - m, d1 = v1 - m, d2 = v2 - m;
  float q = blockSum256(d0 * d0 + d1 * d1 + d2 * d2, red);
  float r = rsqrtf(q * (1.f / 768.f) + EPS_);
  p[t]       = f2bf(d0 * r * g[t]       + bb[t]);
  p[t + 256] = f2bf(d1 * r * g[t + 256] + bb[t + 256]);
  p[t + 512] = f2bf(d2 * r * g[t + 512] + bb[t + 512]);
}

// ---------------------------------------------------------------------------
// MFMA bf16 GEMM: C[M,N] = [C +] act(A @ W^T + bias). 256x256 tile, 512 thr
// (8 waves 2Mx4N; wave = 128x64 via 8x4 of 16x16x32 MFMA), BK=64 dbuf.
// K mult of 64 with K/64 >= 2, N mult of 256. LDS rows are 64 ushorts
// (128 B = bank wrap): 16B group g of row lives at slot g^(row&7).
// Counted-vmcnt pipeline: tile kt+2 staged into the buffer freed by tile kt;
// s_waitcnt vmcnt(8) waits only tile kt+1's loads (full-tile cover), never 0.
template <int ACT, bool ADD>
__global__ __launch_bounds__(512, 2) void gemm_mfma(
    const unsigned short* __restrict__ A, int lda, int K,
    const unsigned short* __restrict__ W, int ldw,
    const float* __restrict__ bias,
    unsigned short* __restrict__ C, int ldc,
    const int* __restrict__ mi) {
  const int rows = mi[MI_NTOT] * 64;
  const int row0 = blockIdx.x * 256;
  if (row0 >= rows) return;
  const int col0 = blockIdx.y * 256;
  __shared__ unsigned short As[2][256 * 64];
  __shared__ unsigned short Bs[2][256 * 64];
  const int t = threadIdx.x;            // 0..511
  const int lane = t & 63, w = t >> 6;  // 8 waves
  const int wr = w >> 2, wc = w & 3;    // 2 x 4 wave grid
  const int quad = lane >> 4, l15 = lane & 15;

  // staging coords: thread t handles chunk c = ph*512 + t (ph = 0..3);
  // row = ph*64 + (t>>3), g = t&7; source group gs = g ^ (row&7) — row&7
  // == (t>>3)&7 since ph*64 is 0 mod 8, so gs is ph-invariant.
  const int srow = t >> 3;              // 0..63
  const int sgs = (t & 7) ^ (srow & 7);
  const unsigned short* aSrc = A + (size_t)(row0 + srow) * lda + sgs * 8;
  const unsigned short* bSrc = W + (size_t)(col0 + srow) * ldw + sgs * 8;

#define STAGE_(ph, kk, Ad, Bd)                                                  \
  do {                                                                          \
    __builtin_amdgcn_global_load_lds(                                           \
        (const __attribute__((address_space(1))) void*)(aSrc + (size_t)(ph) * 64 * lda + (kk)), \
        (__attribute__((address_space(3))) void*)((Ad) + (ph) * 4096 + w * 512), 16, 0, 0); \
    __builtin_amdgcn_global_load_lds(                                           \
        (const __attribute__((address_space(1))) void*)(bSrc + (size_t)(ph) * 64 * ldw + (kk)), \
        (__attribute__((address_space(3))) void*)((Bd) + (ph) * 4096 + w * 512), 16, 0, 0); \
  } while (0)
#define STAGEALL_(kk, Ad, Bd)                                                   \
  do { STAGE_(0, kk, Ad, Bd); STAGE_(1, kk, Ad, Bd);                            \
       STAGE_(2, kk, Ad, Bd); STAGE_(3, kk, Ad, Bd); } while (0)

  auto LDA_ = [&](const unsigned short* buf, int m, int ks) -> short8 {
    const int ar = wr * 128 + m * 16 + l15;
    return *(const short8*)(buf + ar * 64 + (((ks << 2) + quad) ^ (ar & 7)) * 8);
  };
  auto LDB_ = [&](const unsigned short* buf, int n, int ks) -> short8 {
    const int bn = wc * 64 + n * 16 + l15;
    return *(const short8*)(buf + bn * 64 + (((ks << 2) + quad) ^ (bn & 7)) * 8);
  };

  f32x4 acc[8][4];
  #pragma unroll
  for (int m = 0; m < 8; m++)
    #pragma unroll
    for (int n = 0; n < 4; n++) acc[m][n] = (f32x4){0.f, 0.f, 0.f, 0.f};

  // prologue: stage tiles 0 and 1 (KT >= 2 at all call sites: K in {768,2048})
  STAGEALL_(0, As[0], Bs[0]);
  STAGEALL_(64, As[1], Bs[1]);
  asm volatile("s_waitcnt vmcnt(8)" ::: "memory");   // tile 0 landed; tile 1 in flight
  __builtin_amdgcn_sched_barrier(0);
  __builtin_amdgcn_s_barrier();
  __builtin_amdgcn_sched_barrier(0);

  const int KT = K >> 6;
  for (int kt = 0; kt < KT; ++kt) {
    const unsigned short* Ac = As[kt & 1];
    const unsigned short* Bc = Bs[kt & 1];
    short8 afr[4], bfr[4];

    // ---- cluster 1: m 0-3, ks 0 ----
    #pragma unroll
    for (int n = 0; n < 4; n++) bfr[n] = LDB_(Bc, n, 0);
    #pragma unroll
    for (int m = 0; m < 4; m++) afr[m] = LDA_(Ac, m, 0);
    __builtin_amdgcn_s_setprio(1);
    #pragma unroll
    for (int m = 0; m < 4; m++)
      #pragma unroll
      for (int n = 0; n < 4; n++)
        acc[m][n] = __builtin_amdgcn_mfma_f32_16x16x32_bf16(afr[m], bfr[n], acc[m][n], 0, 0, 0);
    __builtin_amdgcn_s_setprio(0);

    // ---- cluster 2: m 4-7, ks 0 (B frags reused) ----
    #pragma unroll
    for (int m = 0; m < 4; m++) afr[m] = LDA_(Ac, m + 4, 0);
    __builtin_amdgcn_s_setprio(1);
    #pragma unroll
    for (int m = 0; m < 4; m++)
      #pragma unroll
      for (int n = 0; n < 4; n++)
        acc[m + 4][n] = __builtin_amdgcn_mfma_f32_16x16x32_bf16(afr[m], bfr[n], acc[m + 4][n], 0, 0, 0);
    __builtin_amdgcn_s_setprio(0);

    // ---- cluster 3: m 0-3, ks 1 ----
    #pragma unroll
    for (int n = 0; n < 4; n++) bfr[n] = LDB_(Bc, n, 1);
    #pragma unroll
    for (int m = 0; m < 4; m++) afr[m] = LDA_(Ac, m, 1);
    __builtin_amdgcn_s_setprio(1);
    #pragma unroll
    for (int m = 0; m < 4; m++)
      #pragma unroll
      for (int n = 0; n < 4; n++)
        acc[m][n] = __builtin_amdgcn_mfma_f32_16x16x32_bf16(afr[m], bfr[n], acc[m][n], 0, 0, 0);
    __builtin_amdgcn_s_setprio(0);

    // ---- cluster 4: m 4-7, ks 1 ----
    #pragma unroll
    for (int m = 0; m < 4; m++) afr[m] = LDA_(Ac, m + 4, 1);
    __builtin_amdgcn_s_setprio(1);
    #pragma unroll
    for (int m = 0; m < 4; m++)
      #pragma unroll
      for (int n = 0; n < 4; n++)
        acc[m + 4][n] = __builtin_amdgcn_mfma_f32_16x16x32_bf16(afr[m], bfr[n], acc[m + 4][n], 0, 0, 0);
    __builtin_amdgcn_s_setprio(0);

    if (kt + 1 < KT) {
      // barrier1: every wave's ds_reads of buf[kt&1] completed (enforced by
      // the compiler's lgkmcnt waits feeding the MFMAs above)
      __builtin_amdgcn_sched_barrier(0);
      __builtin_amdgcn_s_barrier();
      __builtin_amdgcn_sched_barrier(0);
      if (kt + 2 < KT) {
        STAGEALL_((kt + 2) << 6, As[kt & 1], Bs[kt & 1]);   // freed buffer
        // outstanding = 8 (tile kt+1) + 8 (tile kt+2); wait the oldest 8
        asm volatile("s_waitcnt vmcnt(8)" ::: "memory");
      } else {
        // no more staging; tile kt+1's loads had a full tile of cover
        asm volatile("s_waitcnt vmcnt(0)" ::: "memory");
      }
      __builtin_amdgcn_sched_barrier(0);
      __builtin_amdgcn_s_barrier();   // tile kt+1 collectively visible
      __builtin_amdgcn_sched_barrier(0);
    }
  }
#undef STAGEALL_
#undef STAGE_

  // epilogue: C/D layout col = lane&15, row = quad*4 + reg
  float bv[4];
  #pragma unroll
  for (int n = 0; n < 4; n++) bv[n] = bias[col0 + wc * 64 + n * 16 + l15];
  #pragma unroll
  for (int m = 0; m < 8; m++) {
    #pragma unroll
    for (int reg = 0; reg < 4; reg++) {
      const size_t cr = (size_t)(row0 + wr * 128 + m * 16 + quad * 4 + reg) * ldc;
      #pragma unroll
      for (int n = 0; n < 4; n++) {
        const int cn = col0 + wc * 64 + n * 16 + l15;
        float x = acc[m][n][reg] + bv[n];
        if (ACT == 1) x = fmaxf(x, 0.f);
        if (ADD) x += bf2f(C[cr + cn]);
        C[cr + cn] = f2bf(x);
      }
    }
  }
}

// ---------------------------------------------------------------------------
// VALU GEMM (kept for ragged pe/pd only): C = act(A @ W^T + b)
// AT: 0 fp32 A, 1 bf16 A.  CT: 0 fp32 C, 1 bf16 C.
template <int ACT, int AT, int CT>
__global__ __launch_bounds__(256) void gemm_kernel(
    const void* __restrict__ Av, int lda, int kloop,
    const float* __restrict__ W, int kw, int nreal,
    const float* __restrict__ bias,
    void* __restrict__ Cv, int ldc,
    const int* __restrict__ mi) {
  if ((int)blockIdx.x >= mi[MI_NTOT]) return;
  __shared__ float As[16][68];
  __shared__ float Ws[16][68];
  const int t = threadIdx.x;
  const int tx = t & 15, ty = t >> 4;
  const int lrow = t >> 2, lkg = (t & 3) * 4;
  const size_t row0 = (size_t)blockIdx.x * 64;
  const int col0 = blockIdx.y * 64;
  float acc[4][4] = {};
  for (int k0 = 0; k0 < kloop; k0 += 16) {
    float a4[4];
    if (AT == 0) {
      float4 av = *(const float4*)((const float*)Av + (row0 + lrow) * (size_t)lda + k0 + lkg);
      a4[0] = av.x; a4[1] = av.y; a4[2] = av.z; a4[3] = av.w;
    } else {
      uint2 u = *(const uint2*)((const unsigned short*)Av + (row0 + lrow) * (size_t)lda + k0 + lkg);
      a4[0] = bf2f(u.x); a4[1] = bf2f(u.x >> 16);
      a4[2] = bf2f(u.y); a4[3] = bf2f(u.y >> 16);
    }
    float wv[4];
    const int wn = col0 + lrow;
    #pragma unroll
    for (int i = 0; i < 4; i++) {
      const int k = k0 + lkg + i;
      wv[i] = (wn < nreal && k < kw) ? W[(size_t)wn * kw + k] : 0.f;
    }
    __syncthreads();
    As[lkg + 0][lrow] = a4[0]; As[lkg + 1][lrow] = a4[1];
    As[lkg + 2][lrow] = a4[2]; As[lkg + 3][lrow] = a4[3];
    Ws[lkg + 0][lrow] = wv[0]; Ws[lkg + 1][lrow] = wv[1];
    Ws[lkg + 2][lrow] = wv[2]; Ws[lkg + 3][lrow] = wv[3];
    __syncthreads();
    #pragma unroll
    for (int kk = 0; kk < 16; kk++) {
      float4 av4 = *(const float4*)(&As[kk][ty * 4]);
      float4 wv4 = *(const float4*)(&Ws[kk][tx * 4]);
      float aa[4] = {av4.x, av4.y, av4.z, av4.w};
      float ww[4] = {wv4.x, wv4.y, wv4.z, wv4.w};
      #pragma unroll
      for (int i = 0; i < 4; i++)
        #pragma unroll
        for (int j = 0; j < 4; j++) acc[i][j] += aa[i] * ww[j];
    }
  }
  const int n0 = col0 + tx * 4;
  float bv[4];
  #pragma unroll
  for (int j = 0; j < 4; j++) bv[j] = (n0 + j < nreal) ? bias[n0 + j] : 0.f;
  #pragma unroll
  for (int i = 0; i < 4; i++) {
    float v[4];
    #pragma unroll
    for (int j = 0; j < 4; j++) {
      float x = acc[i][j] + bv[j];
      if (ACT == 1) x = fmaxf(x, 0.f);
      if (ACT == 2) x = tanhf(x);
      v[j] = x;
    }
    if (CT == 0) {
      float* cp = (float*)Cv + (row0 + ty * 4 + i) * (size_t)ldc + n0;
      *(float4*)cp = make_float4(v[0], v[1], v[2], v[3]);
    } else {
      unsigned short* cp = (unsigned short*)Cv + (row0 + ty * 4 + i) * (size_t)ldc + n0;
      uint2 pk; pk.x = pack2(v[0], v[1]); pk.y = pack2(v[2], v[3]);
      *(uint2*)cp = pk;
    }
  }
}

// ---------------------------------------------------------------------------
// Pipelined MFMA flash attention per (l,h) [blockIdx.x] x nt [blockIdx.y].
// 4 waves; wave w owns q rows w*16..w*16+15. K double-buffered via
// global_load_lds; V double-buffered via reg-staging (issue-early global
// loads, scatter-late into transposed Vt — round-3-proven layout).
// ONE __syncthreads per key tile (drains vmcnt -> prefetches complete).
__global__ __launch_bounds__(256) void attn_kernel(
    unsigned short* __restrict__ QKV, const float* __restrict__ bias2,
    const int* __restrict__ mi) {
  const int ntot = mi[MI_NTOT];
  const int lh = blockIdx.x, nt = blockIdx.y;
  if (nt * 64 >= ntot) return;
  const int l = lh / H_, h = lh - l * H_;
  __shared__ unsigned short QPs[64 * 64];   // Q staging, then P (per-wave rows)
  __shared__ unsigned short Ks0[64 * 64], Ks1[64 * 64];
  __shared__ unsigned short Vt0[64 * 64], Vt1[64 * 64];  // V^T [d][key], swizzled
  __shared__ float Bls[512];
  const int t = threadIdx.x;
  const int lane = t & 63, w = t >> 6;
  const int quad = lane >> 4, l15 = lane & 15;
  const int q0 = nt * 64;
  const size_t TSTRIDE = (size_t)64 * L_ * 2304;   // elems per 64-key tile

  // per-lane source coords: K row-swizzled chunks, V row loads for scatter
  const unsigned short* ksrc[2];
  const unsigned short* vsrc[2];
  int vg[2], vkey[2];
  #pragma unroll
  for (int r = 0; r < 2; r++) {
    const int c = r * 256 + w * 64 + lane;
    const int row = c >> 3, g = c & 7, gs = g ^ (row & 7);
    ksrc[r] = QKV + (size_t)(row * L_ + l) * 2304 + 768 + h * 64 + gs * 8;
    const int cv = r * 256 + t;
    vg[r] = cv >> 6; vkey[r] = cv & 63;
    vsrc[r] = QKV + (size_t)(vkey[r] * L_ + l) * 2304 + 1536 + h * 64 + vg[r] * 8;
  }
  const unsigned ldst = (unsigned)(w * 512);   // wave-uniform dest elem base

  auto stageK = [&](int mt, unsigned short* Kw) {
    #pragma unroll
    for (int r = 0; r < 2; r++)
      __builtin_amdgcn_global_load_lds(
          (const __attribute__((address_space(1))) void*)(ksrc[r] + (size_t)mt * TSTRIDE),
          (__attribute__((address_space(3))) void*)(Kw + ldst + r * 2048), 16, 0, 0);
  };
  auto scatterV = [&](uint4 a0, uint4 a1, unsigned short* Vw) {
    const unsigned short* p0 = (const unsigned short*)&a0;
    const unsigned short* p1 = (const unsigned short*)&a1;
    #pragma unroll
    for (int j = 0; j < 8; j++) {
      const int d0 = vg[0] * 8 + j;
      Vw[d0 * 64 + ((vkey[0] >> 3) ^ (d0 & 7)) * 8 + (vkey[0] & 7)] = p0[j];
      const int d1 = vg[1] * 8 + j;
      Vw[d1 * 64 + ((vkey[1] >> 3) ^ (d1 & 7)) * 8 + (vkey[1] & 7)] = p1[j];
    }
  };

  // prologue: stage Q + K0 (LDS-DMA), V0 -> regs, bias row -> LDS
  #pragma unroll
  for (int r = 0; r < 2; r++) {
    const int c = r * 256 + w * 64 + lane;
    const int row = c >> 3, g = c & 7, gs = g ^ (row & 7);
    const unsigned short* gq =
        QKV + (size_t)((q0 + row) * L_ + l) * 2304 + h * 64 + gs * 8;
    __builtin_amdgcn_global_load_lds(
        (const __attribute__((address_space(1))) void*)gq,
        (__attribute__((address_space(3))) void*)(QPs + ldst + r * 2048), 16, 0, 0);
  }
  stageK(0, Ks0);
  uint4 pv0 = *(const uint4*)vsrc[0];
  uint4 pv1 = *(const uint4*)vsrc[1];
  for (int idx = t; idx < 512; idx += 256) Bls[idx] = bias2[idx * 64 + l];
  __syncthreads();                       // Q,K0 in LDS; pv regs loaded

  // Q fragments (loop-invariant): A-operand row = l15, k = quad*8..+7
  const int qrow = w * 16 + l15;
  short8 aq[2];
  #pragma unroll
  for (int kq = 0; kq < 2; kq++)
    aq[kq] = *(const short8*)(QPs + qrow * 64 + ((kq * 4 + quad) ^ (qrow & 7)) * 8);
  scatterV(pv0, pv1, Vt0);
  __syncthreads();                       // Vt0 visible; aq read before P reuse

  float runmax[4], runsum[4];
  f32x4 oacc[4];
  #pragma unroll
  for (int i = 0; i < 4; i++) {
    runmax[i] = -3.0e38f; runsum[i] = 0.f;
    oacc[i] = (f32x4){0.f, 0.f, 0.f, 0.f};
  }

  auto tilecomp = [&](int mt, const unsigned short* Krd, const unsigned short* Vrd) {
    // ---- S = Q K^T ----
    f32x4 sa[4];
    #pragma unroll
    for (int n = 0; n < 4; n++) sa[n] = (f32x4){0.f, 0.f, 0.f, 0.f};
    __builtin_amdgcn_s_setprio(1);
    #pragma unroll
    for (int n = 0; n < 4; n++) {
      const int kr = n * 16 + l15;
      #pragma unroll
      for (int kq = 0; kq < 2; kq++) {
        const short8 bk = *(const short8*)(Krd + kr * 64 + ((kq * 4 + quad) ^ (kr & 7)) * 8);
        sa[n] = __builtin_amdgcn_mfma_f32_16x16x32_bf16(aq[kq], bk, sa[n], 0, 0, 0);
      }
    }
    __builtin_amdgcn_s_setprio(0);
    float bj[4];
    #pragma unroll
    for (int n = 0; n < 4; n++) bj[n] = Bls[mt * 64 + n * 16 + l15];
    #pragma unroll
    for (int n = 0; n < 4; n++)
      #pragma unroll
      for (int reg = 0; reg < 4; reg++)
        sa[n][reg] = sa[n][reg] * 0.125f + bj[n];

    // ---- online softmax (rows q = quad*4+reg; reduce over 16-lane group) ----
    float rmax[4], psum[4];
    #pragma unroll
    for (int reg = 0; reg < 4; reg++)
      rmax[reg] = fmaxf(fmaxf(sa[0][reg], sa[1][reg]), fmaxf(sa[2][reg], sa[3][reg]));
    #pragma unroll
    for (int o = 1; o < 16; o <<= 1)
      #pragma unroll
      for (int reg = 0; reg < 4; reg++)
        rmax[reg] = fmaxf(rmax[reg], __shfl_xor(rmax[reg], o));
    #pragma unroll
    for (int reg = 0; reg < 4; reg++) {
      const float nm = fmaxf(runmax[reg], rmax[reg]);
      const float alpha = __expf(runmax[reg] - nm);
      runmax[reg] = nm;
      float s0 = 0.f;
      #pragma unroll
      for (int n = 0; n < 4; n++) {
        const float p = __expf(sa[n][reg] - nm);
        sa[n][reg] = p; s0 += p;
      }
      psum[reg] = s0;
      runsum[reg] *= alpha;
      #pragma unroll
      for (int dn = 0; dn < 4; dn++) oacc[dn][reg] *= alpha;
    }
    #pragma unroll
    for (int o = 1; o < 16; o <<= 1)
      #pragma unroll
      for (int reg = 0; reg < 4; reg++) psum[reg] += __shfl_xor(psum[reg], o);
    #pragma unroll
    for (int reg = 0; reg < 4; reg++) runsum[reg] += psum[reg];

    // ---- P -> LDS bf16 (wave-private rows; in-wave DS order suffices) ----
    #pragma unroll
    for (int n = 0; n < 4; n++) {
      const int key = n * 16 + l15;
      #pragma unroll
      for (int reg = 0; reg < 4; reg++) {
        const int qr = w * 16 + quad * 4 + reg;
        QPs[qr * 64 + ((key >> 3) ^ (qr & 7)) * 8 + (key & 7)] = f2bf(sa[n][reg]);
      }
    }
    short8 ap[2];
    #pragma unroll
    for (int kq = 0; kq < 2; kq++)
      ap[kq] = *(const short8*)(QPs + qrow * 64 + ((kq * 4 + quad) ^ (qrow & 7)) * 8);

    // ---- O += P V  (B rows = Vt rows d = dn*16+l15, keys via chunk XOR) ----
    __builtin_amdgcn_s_setprio(1);
    #pragma unroll
    for (int dn = 0; dn < 4; dn++) {
      const int dr = dn * 16 + l15;
      #pragma unroll
      for (int kq = 0; kq < 2; kq++) {
        const short8 bv = *(const short8*)(Vrd + dr * 64 + ((kq * 4 + quad) ^ (dr & 7)) * 8);
        oacc[dn] = __builtin_amdgcn_mfma_f32_16x16x32_bf16(ap[kq], bv, oacc[dn], 0, 0, 0);
      }
    }
    __builtin_amdgcn_s_setprio(0);
  };

  for (int mt2 = 0; mt2 < 8; mt2 += 2) {
    {   // even step: compute (Ks0,Vt0); prefetch tile mt2+1 into (Ks1,Vt1)
      stageK(mt2 + 1, Ks1);
      uint4 n0 = *(const uint4*)(vsrc[0] + (size_t)(mt2 + 1) * TSTRIDE);
      uint4 n1 = *(const uint4*)(vsrc[1] + (size_t)(mt2 + 1) * TSTRIDE);
      tilecomp(mt2, Ks0, Vt0);
      scatterV(n0, n1, Vt1);
      __syncthreads();   // Ks1 DMA drained + Vt1 scatters visible
    }
    {   // odd step: compute (Ks1,Vt1); prefetch tile mt2+2 into (Ks0,Vt0)
      const bool more = (mt2 + 2) < 8;
      uint4 n0 = make_uint4(0, 0, 0, 0), n1 = make_uint4(0, 0, 0, 0);
      if (more) {
        stageK(mt2 + 2, Ks0);
        n0 = *(const uint4*)(vsrc[0] + (size_t)(mt2 + 2) * TSTRIDE);
        n1 = *(const uint4*)(vsrc[1] + (size_t)(mt2 + 2) * TSTRIDE);
      }
      tilecomp(mt2 + 1, Ks1, Vt1);
      if (more) scatterV(n0, n1, Vt0);
      __syncthreads();
    }
  }

  // epilogue: O rows q = quad*4+reg, cols d = dn*16+l15
  #pragma unroll
  for (int reg = 0; reg < 4; reg++) {
    const float inv = 1.f / runsum[reg];
    const int q = q0 + w * 16 + quad * 4 + reg;
    unsigned short* op = QKV + (size_t)(q * L_ + l) * 2304 + h * 64;
    #pragma unroll
    for (int dn = 0; dn < 4; dn++)
      op[dn * 16 + l15] = f2bf(oacc[dn][reg] * inv);
  }
}

// ---------------------------------------------------------------------------
__global__ __launch_bounds__(256) void score_kernel(const unsigned short* __restrict__ X,
                                                    const float* __restrict__ em,
                                                    float* __restrict__ Sv) {
  const int j = blockIdx.x;
  const int t = threadIdx.x;
  __shared__ float red[4];
  float part = 0.f;
  for (int c = 0; c < 3; c++) {
    const int d = t + c * 256;
    const unsigned short* p = X + (size_t)j * L_ * D_ + d;
    float s = 0.f;
    for (int l = 0; l < L_; l++) s += bf2f(p[l * D_]);
    const float diff = s * (1.f / 64.f) - em[j * D_ + d];
    part += diff * diff;
  }
  const float tot = blockSum256(part, red);
  if (t == 0) Sv[j] = tot;
}

// ---------------------------------------------------------------------------
__global__ __launch_bounds__(256) void finalize_kernel(const float* __restrict__ Sv,
                                                       int* __restrict__ mi,
                                                       float* __restrict__ out) {
  const int t = threadIdx.x;
  if (t < B_) {
    const int nr = mi[MI_NRESP + t];
    float best = 3.0e38f; int bi = 0;
    for (int j = 0; j < nr; j++) {
      const float v = Sv[j];
      if (v < best) { best = v; bi = j; }
    }
    mi[MI_NODE + t] = bi + 1;
    int next = nr / 20; if (next < 1) next = 1;
    out[OUT_NTL + t] = (float)(1 + next);
  }
  if (t == 0) out[OUT_NEA] = 0.f;
  __syncthreads();
  for (int idx = t; idx < B_ * T_; idx += 256) {
    const int b = idx >> 5, tt = idx & 31;
    out[OUT_OH + idx] = (tt == 0 || tt == mi[MI_NODE + b]) ? 1.f : 0.f;
  }
}

// ---------------------------------------------------------------------------
__global__ __launch_bounds__(256) void maskout_kernel(const float* __restrict__ am,
                                                      const int* __restrict__ mi,
                                                      float* __restrict__ out) {
  const int idx = blockIdx.x * 256 + threadIdx.x;
  const int b = idx >> 11, rem = idx & 2047;
  const int tt = rem >> 6, l = rem & 63;
  const int node = mi[MI_NODE + b];
  out[OUT_EXT + idx] = (tt == 0 || tt == node) ? 1.f : 0.f;
  float nm;
  if (tt == 0)      nm = am[(b * T_) * L_ + l];
  else if (tt == 1) nm = am[(b * T_ + node) * L_ + l];
  else              nm = 0.f;
  out[OUT_NMSK + idx] = nm;
}

// ---------------------------------------------------------------------------
__global__ __launch_bounds__(192) void newemb_kernel(const float* __restrict__ emb,
                                                     const int* __restrict__ mi,
                                                     float* __restrict__ out) {
  const int blk = blockIdx.x;
  const int b = blk >> 11, rem = blk & 2047;
  const int tt = rem >> 6, l = rem & 63;
  const int srct = (tt == 1) ? mi[MI_NODE + b] : 0;
  const float4 v = ((const float4*)(emb + (size_t)((b * T_ + srct) * L_ + l) * D_))[threadIdx.x];
  float* dst = out + OUT_NEMB + (size_t)blk * D_ + threadIdx.x * 4;
  dst[0] = v.x; dst[1] = v.y; dst[2] = v.z; dst[3] = v.w;
}

// ===========================================================================
extern "C" void kernel_launch(void* const* d_in, const int* in_sizes, int n_in,
                              void* d_out, int out_size, void* d_ws, size_t ws_size,
                              hipStream_t stream) {
  (void)in_sizes; (void)n_in; (void)out_size; (void)ws_size;
  const int*   tl  = (const int*)d_in[0];
  const float* emb = (const float*)d_in[1];
  const float* am  = (const float*)d_in[2];
  const float* P[28];
  for (int i = 0; i < 28; i++) P[i] = (const float*)d_in[3 + i];

  float* wsf   = (float*)d_ws;
  int*   mi    = (int*)d_ws;
  float* bias2 = wsf + WS_BIAS2;
  float* emean = wsf + WS_EMEAN;
  float* Sv    = wsf + WS_S;
  unsigned short* Wst = (unsigned short*)(wsf + WS_WST);
  unsigned short* BIG = (unsigned short*)(wsf + WS_BIG);
  float* Zb    = wsf + WS_BIG;                      // fp32 Z overlay (enc->dec)
  float* out   = (float*)d_out;
  unsigned short* X = (unsigned short*)(out + OUT_XSCR);  // bf16 residual

  meta_kernel<<<1, 64, 0, stream>>>(tl, mi);
  gather_kernel<<<NP_ * L_, 192, 0, stream>>>(emb, am, mi, X, bias2);
  emean_kernel<<<NP_, 256, 0, stream>>>(X, emean);
  zerotail_kernel<<<NP_ * L_, 256, 0, stream>>>(mi, BIG);

  const int RT2 = NP_ * 64 / 256;   // 128 row tiles
  for (int s = 0; s < 2; s++) {
    const float* const* q = P + s * 12;
    for (int i = 0; i < 2; i++) {
      // QKV: X -> BIG [rows, 2304]
      w2bf_kernel<<<(3 * D_ * D_) / 1024, 256, 0, stream>>>(q[0] + (size_t)i * 3 * D_ * D_, Wst);
      gemm_mfma<0, false><<<dim3(RT2, 9), 512, 0, stream>>>(
          X, D_, D_, Wst, D_, q[1] + i * 3 * D_, BIG, 3 * D_, mi);
      attn_kernel<<<dim3(L_ * H_, 8), 256, 0, stream>>>(BIG, bias2, mi);
      // out-proj: O (Q cols of BIG, lda=2304) -> += X
      w2bf_kernel<<<(D_ * D_) / 1024, 256, 0, stream>>>(q[2] + (size_t)i * D_ * D_, Wst);
      gemm_mfma<0, true><<<dim3(RT2, 3), 512, 0, stream>>>(
          BIG, 3 * D_, D_, Wst, D_, q[3] + i * D_, X, D_, mi);
      ln_kernel<<<NP_ * L_, 256, 0, stream>>>(X, q[4] + i * D_, q[5] + i * D_, mi);
      // FFN1: X -> hidden BIG [rows, 2048] (relu)
      w2bf_kernel<<<(F_ * D_) / 1024, 256, 0, stream>>>(q[6] + (size_t)i * F_ * D_, Wst);
      gemm_mfma<1, false><<<dim3(RT2, 8), 512, 0, stream>>>(
          X, D_, D_, Wst, D_, q[7] + i * F_, BIG, F_, mi);
      // FFN2: hidden -> += X
      w2bf_kernel<<<(D_ * F_) / 1024, 256, 0, stream>>>(q[8] + (size_t)i * D_ * F_, Wst);
      gemm_mfma<0, true><<<dim3(RT2, 3), 512, 0, stream>>>(
          BIG, F_, F_, Wst, F_, q[9] + i * D_, X, D_, mi);
      ln_kernel<<<NP_ * L_, 256, 0, stream>>>(X, q[10] + i * D_, q[11] + i * D_, mi);
    }
    if (s == 0) {
      // z = tanh(h @ pe_w^T + pe_b) -> Z fp32 (stride 128, cols 100..127 = 0)
      gemm_kernel<2, 1, 0><<<dim3(NP_, 2), 256, 0, stream>>>(
          X, D_, D_, P[24], D_, ZR_, P[25], Zb, ZP_, mi);
      // zd = tanh(z @ pd_w^T + pd_b) -> X bf16 (decoder input)
      gemm_kernel<2, 0, 1><<<dim3(NP_, 12), 256, 0, stream>>>(
          Zb, ZP_, ZP_, P[26], ZR_, D_, P[27], X, D_, mi);
    }
  }

  score_kernel<<<NP_, 256, 0, stream>>>(X, emean, Sv);
  finalize_kernel<<<1, 256, 0, stream>>>(Sv, mi, out);
  maskout_kernel<<<128, 256, 0, stream>>>(am, mi, out);
  newemb_kernel<<<B_ * T_ * L_, 192, 0, stream>>>(emb, mi, out);
}

// Round 6
// 3019.767 us; speedup vs baseline: 1.0331x; 1.0331x over previous
//
#include <hip/hip_runtime.h>
#include <hip/hip_bf16.h>
#include <math.h>

// ============================================================================
// ResponseFilter — round 8: GEMM operand locality + MFMA pe/pd + batched w2bf.
//
// Round-7 post-mortem: counted-vmcnt restructure was neutral/negative (3120 vs
// round-6 2995) — schedule micro-structure is not the lever. Budget analysis:
// MFMA floor per QKV dispatch ~14us vs observed ~100us -> operand RE-FETCH
// bound (grid x=row-fastest puts the 9 blocks sharing an A panel 128 IDs
// apart -> no L2 co-residency; A re-fetched ~9x).
// Changes:
//   - K-loop reverted to round-6 form (interleaved stage issue, 1 barrier).
//   - 1-D grid, chunked XCD swizzle (T1): wg=(id%8)*(NT/8)+id/8, col=wg%CT,
//     row=wg/CT. A-panel sharers land on one XCD's L2.
//   - pe/pd -> gemm_mfma (ACT=2 tanh): pe_w padded to [256][768] bf16,
//     pd_w to [768][256] (K=256, zero-padded), Z bf16 [rows][256].
//   - all 16 weight matrices converted up front (w2bf4 x4) into spare d_out.
// attn unchanged (round-5-proven, 179us).
// ============================================================================

#define B_  16
#define T_  32
#define L_  64
#define D_  768
#define H_  12
#define F_  2048
#define ZR_ 100
#define NP_ 512
#define EPS_ 1e-5f

// meta int offsets (d_ws as int*)
#define MI_NTOT  0
#define MI_NRESP 8
#define MI_OFF   32
#define MI_BIDX  64
#define MI_TIDX  576
#define MI_NODE  1088

// ws float offsets
#define WS_BIAS2 2048
#define WS_EMEAN 34816
#define WS_S     428032
#define WS_WST   428544    // pe/pd padded bf16 weights + padded pe bias
#define WS_BIG   1313280   // bf16 QKV/hidden region; bf16 Z overlay

#define PEB_F    (WS_WST + 196608)   // float offset of padded pe bias [256]

// d_out float offsets (flat tuple: oh[512], ext_mask[32768], n_ext_adv[1],
// new_tree_lens[16], new_emb[25165824], new_msk[32768])
#define OUT_OH   0
#define OUT_EXT  512
#define OUT_NEA  33280
#define OUT_NTL  33281
#define OUT_NEMB 33297
#define OUT_NMSK 25199121
#define OUT_XSCR 33300      // bf16 X scratch, 32768*768 ushorts (ends 12616212)
#define OUT_WSTK 12616224   // bf16 converted weights, 4 passes x 5,505,024 ushorts

// per-pass converted-weight segment sizes (ushorts)
#define WSEG0 1769472   // qkv  [2304][768]
#define WSEG1 589824    // out  [768][768]
#define WSEG2 1572864   // w1   [2048][768]
#define WSEG3 1572864   // w2   [768][2048]
#define WPASS 5505024

typedef __attribute__((ext_vector_type(8))) short short8;
typedef __attribute__((ext_vector_type(4))) float f32x4;

__device__ inline float bf2f(unsigned s) {
  return __uint_as_float((s & 0xffffu) << 16);
}
__device__ inline unsigned short f2bf(float x) {
  unsigned u = __float_as_uint(x);
  u += 0x7fffu + ((u >> 16) & 1u);      // round-to-nearest-even
  return (unsigned short)(u >> 16);
}
__device__ inline unsigned pack2(float a, float b) {
  return (unsigned)f2bf(a) | ((unsigned)f2bf(b) << 16);
}

// ---------------------------------------------------------------------------
__global__ void meta_kernel(const int* __restrict__ tl, int* __restrict__ mi) {
  if (threadIdx.x != 0) return;
  int off = 0;
  for (int b = 0; b < B_; b++) {
    int nr = tl[b] - 1;
    mi[MI_NRESP + b] = nr;
    mi[MI_OFF + b] = off;
    off += nr;
  }
  mi[MI_NTOT] = off;
  for (int j = 0; j < NP_; j++) {
    int b = -1, t = 0;
    if (j < off) {
      b = 0;
      while (b + 1 < B_ && j >= mi[MI_OFF + b + 1]) b++;
      t = j - mi[MI_OFF + b] + 1;
    }
    mi[MI_BIDX + j] = b;
    mi[MI_TIDX + j] = t;
  }
}

// ---------------------------------------------------------------------------
// batched fp32 -> bf16 conversion of one layer-pass's 4 weight matrices.
// grid = WPASS/1024 blocks; segment boundaries are multiples of 1024.
__global__ __launch_bounds__(256) void w2bf4_kernel(
    const float* __restrict__ s0, const float* __restrict__ s1,
    const float* __restrict__ s2, const float* __restrict__ s3,
    unsigned short* __restrict__ dst) {
  const int e = blockIdx.x * 1024 + threadIdx.x * 4;
  const float* src;
  int off;
  if (e < WSEG0)                         { src = s0; off = e; }
  else if (e < WSEG0 + WSEG1)            { src = s1; off = e - WSEG0; }
  else if (e < WSEG0 + WSEG1 + WSEG2)    { src = s2; off = e - WSEG0 - WSEG1; }
  else                                   { src = s3; off = e - WSEG0 - WSEG1 - WSEG2; }
  float4 v = *(const float4*)(src + off);
  uint2 pk; pk.x = pack2(v.x, v.y); pk.y = pack2(v.z, v.w);
  *(uint2*)(dst + e) = pk;
}

// ---------------------------------------------------------------------------
// pe_w [100][768] -> peW [256][768] bf16 (rows >=100 zero)
// pd_w [768][100] -> pdW [768][256] bf16 (cols >=100 zero)
// pe_b [100]      -> peB [256] fp32 (zero-padded)
__global__ __launch_bounds__(256) void pepd_stage(
    const float* __restrict__ pew, const float* __restrict__ peb,
    const float* __restrict__ pdw,
    unsigned short* __restrict__ dpe, unsigned short* __restrict__ dpd,
    float* __restrict__ dpeb) {
  const int blk = blockIdx.x, t = threadIdx.x;
  if (blk < 192) {                       // pe: 196608 elems
    const int e = blk * 1024 + t * 4;
    const int r = e / 768, c = e % 768;
    float v[4];
    #pragma unroll
    for (int j = 0; j < 4; j++) v[j] = (r < ZR_) ? pew[r * 768 + c + j] : 0.f;
    uint2 pk; pk.x = pack2(v[0], v[1]); pk.y = pack2(v[2], v[3]);
    *(uint2*)(dpe + e) = pk;
  } else if (blk < 384) {                // pd: 196608 elems
    const int e = (blk - 192) * 1024 + t * 4;
    const int r = e / 256, c = e % 256;
    float v[4];
    #pragma unroll
    for (int j = 0; j < 4; j++) v[j] = (c + j < ZR_) ? pdw[r * ZR_ + c + j] : 0.f;
    uint2 pk; pk.x = pack2(v[0], v[1]); pk.y = pack2(v[2], v[3]);
    *(uint2*)(dpd + e) = pk;
  } else {                               // bias pad
    dpeb[t] = (t < ZR_) ? peb[t] : 0.f;
  }
}

// ---------------------------------------------------------------------------
// X[j,l,:] bf16 = reply embedding (zero for padded j); bias2 = mask or -1e30
__global__ __launch_bounds__(192) void gather_kernel(
    const float* __restrict__ emb, const float* __restrict__ am,
    const int* __restrict__ mi, unsigned short* __restrict__ X,
    float* __restrict__ bias2) {
  const int blk = blockIdx.x;          // j*64 + l
  const int j = blk >> 6, l = blk & 63;
  const int ntot = mi[MI_NTOT];
  const int t = threadIdx.x;
  float4 v = make_float4(0.f, 0.f, 0.f, 0.f);
  if (j < ntot) {
    const int b = mi[MI_BIDX + j], tt = mi[MI_TIDX + j];
    v = ((const float4*)(emb + (size_t)((b * T_ + tt) * L_ + l) * D_))[t];
    if (t == 0) bias2[blk] = am[(b * T_ + tt) * L_ + l];
  } else {
    if (t == 0) bias2[blk] = -1e30f;
  }
  uint2 pk; pk.x = pack2(v.x, v.y); pk.y = pack2(v.z, v.w);
  *(uint2*)(X + (size_t)blk * D_ + t * 4) = pk;
}

// ---------------------------------------------------------------------------
// zero QKV rows >= ntot*64 in BIG (once per launch): attention reads K/V for
// all 512 padded responses; rows beyond the last GEMM tile must be finite.
__global__ __launch_bounds__(256) void zerotail_kernel(const int* __restrict__ mi,
                                                       unsigned short* __restrict__ BIG) {
  const int row = blockIdx.x;                 // 0 .. 32767
  if (row < mi[MI_NTOT] * 64) return;
  uint4 z = make_uint4(0u, 0u, 0u, 0u);
  uint4* p = (uint4*)(BIG + (size_t)row * 2304);   // 2304 ushorts = 288 uint4
  for (int c = threadIdx.x; c < 288; c += 256) p[c] = z;
}

// ---------------------------------------------------------------------------
__global__ __launch_bounds__(256) void emean_kernel(const unsigned short* __restrict__ X,
                                                    float* __restrict__ em) {
  const int j = blockIdx.x;
  int d = threadIdx.x;
  for (int c = 0; c < 3; c++, d += 256) {
    const unsigned short* p = X + (size_t)j * L_ * D_ + d;
    float s = 0.f;
    for (int l = 0; l < L_; l++) s += bf2f(p[l * D_]);
    em[j * D_ + d] = s * (1.f / 64.f);
  }
}

// ---------------------------------------------------------------------------
__device__ inline float blockSum256(float v, float* red) {
  #pragma unroll
  for (int o = 32; o > 0; o >>= 1) v += __shfl_down(v, o);
  const int lane = threadIdx.x & 63, wid = threadIdx.x >> 6;
  __syncthreads();
  if (lane == 0) red[wid] = v;
  __syncthreads();
  return red[0] + red[1] + red[2] + red[3];
}

// in-place LN (bf16 storage, fp32 stats); skips padded rows
__global__ __launch_bounds__(256) void ln_kernel(unsigned short* __restrict__ X,
                                                 const float* __restrict__ g,
                                                 const float* __restrict__ bb,
                                                 const int* __restrict__ mi) {
  const int row = blockIdx.x;
  if (row >= mi[MI_NTOT] * L_) return;
  unsigned short* p = X + (size_t)row * D_;
  const int t = threadIdx.x;
  __shared__ float red[4];
  float v0 = bf2f(p[t]), v1 = bf2f(p[t + 256]), v2 = bf2f(p[t + 512]);
  float s = blockSum256(v0 + v1 + v2, red);
  float m = s * (1.f / 768.f);
  float d0 = v0 - m, d1 = v1 - m, d2 = v2 - m;
  float q = blockSum256(d0 * d0 + d1 * d1 + d2 * d2, red);
  float r = rsqrtf(q * (1.f / 768.f) + EPS_);
  p[t]       = f2bf(d0 * r * g[t]       + bb[t]);
  p[t + 256] = f2bf(d1 * r * g[t + 256] + bb[t + 256]);
  p[t + 512] = f2bf(d2 * r * g[t + 512] + bb[t + 512]);
}

// ---------------------------------------------------------------------------
// MFMA bf16 GEMM: C[M,N] = [C +] act(A @ W^T + bias). 256x256 tile, 512 thr
// (8 waves 2Mx4N; wave = 128x64 via 8x4 of 16x16x32 MFMA), BK=64 dbuf.
// 1-D grid NT = 128*CT (NT % 8 == 0). Chunked XCD swizzle: wg = (id%8)*(NT/8)
// + id/8; col-fastest decomposition so A-panel sharers land on one XCD's L2.
// LDS rows 64 ushorts (128B = bank wrap): group g of row at slot g^(row&7).
// Round-6 loop: staging for kt+1 interleaved between MFMA clusters of kt.
// ACT: 0 none, 1 relu, 2 tanh.
template <int ACT, bool ADD>
__global__ __launch_bounds__(512, 2) void gemm_mfma(
    const unsigned short* __restrict__ A, int lda, int K,
    const unsigned short* __restrict__ W, int ldw,
    const float* __restrict__ bias,
    unsigned short* __restrict__ C, int ldc, int CT,
    const int* __restrict__ mi) {
  const int rows = mi[MI_NTOT] * 64;
  const int NT = gridDim.x;
  const int id = blockIdx.x;
  const int wg = (id & 7) * (NT >> 3) + (id >> 3);
  const int row0 = (wg / CT) * 256;
  if (row0 >= rows) return;
  const int col0 = (wg % CT) * 256;
  __shared__ unsigned short As[2][256 * 64];
  __shared__ unsigned short Bs[2][256 * 64];
  const int t = threadIdx.x;            // 0..511
  const int lane = t & 63, w = t >> 6;  // 8 waves
  const int wr = w >> 2, wc = w & 3;    // 2 x 4 wave grid
  const int quad = lane >> 4, l15 = lane & 15;

  // staging coords: thread t handles chunk c = ph*512 + t (ph = 0..3);
  // row = ph*64 + (t>>3), g = t&7; source group gs = g ^ (row&7).
  const int srow = t >> 3;              // 0..63
  const int sgs = (t & 7) ^ (srow & 7);
  const unsigned short* aSrc = A + (size_t)(row0 + srow) * lda + sgs * 8;
  const unsigned short* bSrc = W + (size_t)(col0 + srow) * ldw + sgs * 8;

#define STAGE_(ph, kk, Ad, Bd)                                                  \
  do {                                                                          \
    __builtin_amdgcn_global_load_lds(                                           \
        (const __attribute__((address_space(1))) void*)(aSrc + (size_t)(ph) * 64 * lda + (kk)), \
        (__attribute__((address_space(3))) void*)((Ad) + (ph) * 4096 + w * 512), 16, 0, 0); \
    __builtin_amdgcn_global_load_lds(                                           \
        (const __attribute__((address_space(1))) void*)(bSrc + (size_t)(ph) * 64 * ldw + (kk)), \
        (__attribute__((address_space(3))) void*)((Bd) + (ph) * 4096 + w * 512), 16, 0, 0); \
  } while (0)

  auto LDA_ = [&](const unsigned short* buf, int m, int ks) -> short8 {
    const int ar = wr * 128 + m * 16 + l15;
    return *(const short8*)(buf + ar * 64 + (((ks << 2) + quad) ^ (ar & 7)) * 8);
  };
  auto LDB_ = [&](const unsigned short* buf, int n, int ks) -> short8 {
    const int bn = wc * 64 + n * 16 + l15;
    return *(const short8*)(buf + bn * 64 + (((ks << 2) + quad) ^ (bn & 7)) * 8);
  };

  f32x4 acc[8][4];
  #pragma unroll
  for (int m = 0; m < 8; m++)
    #pragma unroll
    for (int n = 0; n < 4; n++) acc[m][n] = (f32x4){0.f, 0.f, 0.f, 0.f};

  // prologue: stage tile 0
  STAGE_(0, 0, As[0], Bs[0]);
  STAGE_(1, 0, As[0], Bs[0]);
  STAGE_(2, 0, As[0], Bs[0]);
  STAGE_(3, 0, As[0], Bs[0]);
  __syncthreads();

  const int KT = K >> 6;
  for (int kt = 0; kt < KT; ++kt) {
    const unsigned short* Ac = As[kt & 1];
    const unsigned short* Bc = Bs[kt & 1];
    unsigned short* An = As[(kt + 1) & 1];
    unsigned short* Bn = Bs[(kt + 1) & 1];
    const int kn = (kt + 1) << 6;
    const bool more = kn < K;
    short8 afr[4], bfr[4];

    // ---- cluster 1: m 0-3, ks 0 ----
    #pragma unroll
    for (int n = 0; n < 4; n++) bfr[n] = LDB_(Bc, n, 0);
    #pragma unroll
    for (int m = 0; m < 4; m++) afr[m] = LDA_(Ac, m, 0);
    if (more) STAGE_(0, kn, An, Bn);
    __builtin_amdgcn_s_setprio(1);
    #pragma unroll
    for (int m = 0; m < 4; m++)
      #pragma unroll
      for (int n = 0; n < 4; n++)
        acc[m][n] = __builtin_amdgcn_mfma_f32_16x16x32_bf16(afr[m], bfr[n], acc[m][n], 0, 0, 0);
    __builtin_amdgcn_s_setprio(0);

    // ---- cluster 2: m 4-7, ks 0 (B frags reused) ----
    #pragma unroll
    for (int m = 0; m < 4; m++) afr[m] = LDA_(Ac, m + 4, 0);
    if (more) STAGE_(1, kn, An, Bn);
    __builtin_amdgcn_s_setprio(1);
    #pragma unroll
    for (int m = 0; m < 4; m++)
      #pragma unroll
      for (int n = 0; n < 4; n++)
        acc[m + 4][n] = __builtin_amdgcn_mfma_f32_16x16x32_bf16(afr[m], bfr[n], acc[m + 4][n], 0, 0, 0);
    __builtin_amdgcn_s_setprio(0);

    // ---- cluster 3: m 0-3, ks 1 ----
    #pragma unroll
    for (int n = 0; n < 4; n++) bfr[n] = LDB_(Bc, n, 1);
    #pragma unroll
    for (int m = 0; m < 4; m++) afr[m] = LDA_(Ac, m, 1);
    if (more) STAGE_(2, kn, An, Bn);
    __builtin_amdgcn_s_setprio(1);
    #pragma unroll
    for (int m = 0; m < 4; m++)
      #pragma unroll
      for (int n = 0; n < 4; n++)
        acc[m][n] = __builtin_amdgcn_mfma_f32_16x16x32_bf16(afr[m], bfr[n], acc[m][n], 0, 0, 0);
    __builtin_amdgcn_s_setprio(0);

    // ---- cluster 4: m 4-7, ks 1 ----
    #pragma unroll
    for (int m = 0; m < 4; m++) afr[m] = LDA_(Ac, m + 4, 1);
    if (more) STAGE_(3, kn, An, Bn);
    __builtin_amdgcn_s_setprio(1);
    #pragma unroll
    for (int m = 0; m < 4; m++)
      #pragma unroll
      for (int n = 0; n < 4; n++)
        acc[m + 4][n] = __builtin_amdgcn_mfma_f32_16x16x32_bf16(afr[m], bfr[n], acc[m + 4][n], 0, 0, 0);
    __builtin_amdgcn_s_setprio(0);

    __syncthreads();   // drains kt+1 staging (issued early) + swap
  }
#undef STAGE_

  // epilogue: C/D layout col = lane&15, row = quad*4 + reg
  float bv[4];
  #pragma unroll
  for (int n = 0; n < 4; n++) bv[n] = bias[col0 + wc * 64 + n * 16 + l15];
  #pragma unroll
  for (int m = 0; m < 8; m++) {
    #pragma unroll
    for (int reg = 0; reg < 4; reg++) {
      const size_t cr = (size_t)(row0 + wr * 128 + m * 16 + quad * 4 + reg) * ldc;
      #pragma unroll
      for (int n = 0; n < 4; n++) {
        const int cn = col0 + wc * 64 + n * 16 + l15;
        float x = acc[m][n][reg] + bv[n];
        if (ACT == 1) x = fmaxf(x, 0.f);
        if (ACT == 2) x = tanhf(x);
        if (ADD) x += bf2f(C[cr + cn]);
        C[cr + cn] = f2bf(x);
      }
    }
  }
}

// ---------------------------------------------------------------------------
// Pipelined MFMA flash attention per (l,h) [blockIdx.x] x nt [blockIdx.y].
// 4 waves; wave w owns q rows w*16..w*16+15. K double-buffered via
// global_load_lds; V double-buffered via reg-staging (issue-early global
// loads, scatter-late into transposed Vt). ONE __syncthreads per key tile.
__global__ __launch_bounds__(256) void attn_kernel(
    unsigned short* __restrict__ QKV, const float* __restrict__ bias2,
    const int* __restrict__ mi) {
  const int ntot = mi[MI_NTOT];
  const int lh = blockIdx.x, nt = blockIdx.y;
  if (nt * 64 >= ntot) return;
  const int l = lh / H_, h = lh - l * H_;
  __shared__ unsigned short QPs[64 * 64];   // Q staging, then P (per-wave rows)
  __shared__ unsigned short Ks0[64 * 64], Ks1[64 * 64];
  __shared__ unsigned short Vt0[64 * 64], Vt1[64 * 64];  // V^T [d][key], swizzled
  __shared__ float Bls[512];
  const int t = threadIdx.x;
  const int lane = t & 63, w = t >> 6;
  const int quad = lane >> 4, l15 = lane & 15;
  const int q0 = nt * 64;
  const size_t TSTRIDE = (size_t)64 * L_ * 2304;   // elems per 64-key tile

  // per-lane source coords: K row-swizzled chunks, V row loads for scatter
  const unsigned short* ksrc[2];
  const unsigned short* vsrc[2];
  int vg[2], vkey[2];
  #pragma unroll
  for (int r = 0; r < 2; r++) {
    const int c = r * 256 + w * 64 + lane;
    const int row = c >> 3, g = c & 7, gs = g ^ (row & 7);
    ksrc[r] = QKV + (size_t)(row * L_ + l) * 2304 + 768 + h * 64 + gs * 8;
    const int cv = r * 256 + t;
    vg[r] = cv >> 6; vkey[r] = cv & 63;
    vsrc[r] = QKV + (size_t)(vkey[r] * L_ + l) * 2304 + 1536 + h * 64 + vg[r] * 8;
  }
  const unsigned ldst = (unsigned)(w * 512);   // wave-uniform dest elem base

  auto stageK = [&](int mt, unsigned short* Kw) {
    #pragma unroll
    for (int r = 0; r < 2; r++)
      __builtin_amdgcn_global_load_lds(
          (const __attribute__((address_space(1))) void*)(ksrc[r] + (size_t)mt * TSTRIDE),
          (__attribute__((address_space(3))) void*)(Kw + ldst + r * 2048), 16, 0, 0);
  };
  auto scatterV = [&](uint4 a0, uint4 a1, unsigned short* Vw) {
    const unsigned short* p0 = (const unsigned short*)&a0;
    const unsigned short* p1 = (const unsigned short*)&a1;
    #pragma unroll
    for (int j = 0; j < 8; j++) {
      const int d0 = vg[0] * 8 + j;
      Vw[d0 * 64 + ((vkey[0] >> 3) ^ (d0 & 7)) * 8 + (vkey[0] & 7)] = p0[j];
      const int d1 = vg[1] * 8 + j;
      Vw[d1 * 64 + ((vkey[1] >> 3) ^ (d1 & 7)) * 8 + (vkey[1] & 7)] = p1[j];
    }
  };

  // prologue: stage Q + K0 (LDS-DMA), V0 -> regs, bias row -> LDS
  #pragma unroll
  for (int r = 0; r < 2; r++) {
    const int c = r * 256 + w * 64 + lane;
    const int row = c >> 3, g = c & 7, gs = g ^ (row & 7);
    const unsigned short* gq =
        QKV + (size_t)((q0 + row) * L_ + l) * 2304 + h * 64 + gs * 8;
    __builtin_amdgcn_global_load_lds(
        (const __attribute__((address_space(1))) void*)gq,
        (__attribute__((address_space(3))) void*)(QPs + ldst + r * 2048), 16, 0, 0);
  }
  stageK(0, Ks0);
  uint4 pv0 = *(const uint4*)vsrc[0];
  uint4 pv1 = *(const uint4*)vsrc[1];
  for (int idx = t; idx < 512; idx += 256) Bls[idx] = bias2[idx * 64 + l];
  __syncthreads();                       // Q,K0 in LDS; pv regs loaded

  // Q fragments (loop-invariant): A-operand row = l15, k = quad*8..+7
  const int qrow = w * 16 + l15;
  short8 aq[2];
  #pragma unroll
  for (int kq = 0; kq < 2; kq++)
    aq[kq] = *(const short8*)(QPs + qrow * 64 + ((kq * 4 + quad) ^ (qrow & 7)) * 8);
  scatterV(pv0, pv1, Vt0);
  __syncthreads();                       // Vt0 visible; aq read before P reuse

  float runmax[4], runsum[4];
  f32x4 oacc[4];
  #pragma unroll
  for (int i = 0; i < 4; i++) {
    runmax[i] = -3.0e38f; runsum[i] = 0.f;
    oacc[i] = (f32x4){0.f, 0.f, 0.f, 0.f};
  }

  auto tilecomp = [&](int mt, const unsigned short* Krd, const unsigned short* Vrd) {
    // ---- S = Q K^T ----
    f32x4 sa[4];
    #pragma unroll
    for (int n = 0; n < 4; n++) sa[n] = (f32x4){0.f, 0.f, 0.f, 0.f};
    __builtin_amdgcn_s_setprio(1);
    #pragma unroll
    for (int n = 0; n < 4; n++) {
      const int kr = n * 16 + l15;
      #pragma unroll
      for (int kq = 0; kq < 2; kq++) {
        const short8 bk = *(const short8*)(Krd + kr * 64 + ((kq * 4 + quad) ^ (kr & 7)) * 8);
        sa[n] = __builtin_amdgcn_mfma_f32_16x16x32_bf16(aq[kq], bk, sa[n], 0, 0, 0);
      }
    }
    __builtin_amdgcn_s_setprio(0);
    float bj[4];
    #pragma unroll
    for (int n = 0; n < 4; n++) bj[n] = Bls[mt * 64 + n * 16 + l15];
    #pragma unroll
    for (int n = 0; n < 4; n++)
      #pragma unroll
      for (int reg = 0; reg < 4; reg++)
        sa[n][reg] = sa[n][reg] * 0.125f + bj[n];

    // ---- online softmax (rows q = quad*4+reg; reduce over 16-lane group) ----
    float rmax[4], psum[4];
    #pragma unroll
    for (int reg = 0; reg < 4; reg++)
      rmax[reg] = fmaxf(fmaxf(sa[0][reg], sa[1][reg]), fmaxf(sa[2][reg], sa[3][reg]));
    #pragma unroll
    for (int o = 1; o < 16; o <<= 1)
      #pragma unroll
      for (int reg = 0; reg < 4; reg++)
        rmax[reg] = fmaxf(rmax[reg], __shfl_xor(rmax[reg], o));
    #pragma unroll
    for (int reg = 0; reg < 4; reg++) {
      const float nm = fmaxf(runmax[reg], rmax[reg]);
      const float alpha = __expf(runmax[reg] - nm);
      runmax[reg] = nm;
      float s0 = 0.f;
      #pragma unroll
      for (int n = 0; n < 4; n++) {
        const float p = __expf(sa[n][reg] - nm);
        sa[n][reg] = p; s0 += p;
      }
      psum[reg] = s0;
      runsum[reg] *= alpha;
      #pragma unroll
      for (int dn = 0; dn < 4; dn++) oacc[dn][reg] *= alpha;
    }
    #pragma unroll
    for (int o = 1; o < 16; o <<= 1)
      #pragma unroll
      for (int reg = 0; reg < 4; reg++) psum[reg] += __shfl_xor(psum[reg], o);
    #pragma unroll
    for (int reg = 0; reg < 4; reg++) runsum[reg] += psum[reg];

    // ---- P -> LDS bf16 (wave-private rows; in-wave DS order suffices) ----
    #pragma unroll
    for (int n = 0; n < 4; n++) {
      const int key = n * 16 + l15;
      #pragma unroll
      for (int reg = 0; reg < 4; reg++) {
        const int qr = w * 16 + quad * 4 + reg;
        QPs[qr * 64 + ((key >> 3) ^ (qr & 7)) * 8 + (key & 7)] = f2bf(sa[n][reg]);
      }
    }
    short8 ap[2];
    #pragma unroll
    for (int kq = 0; kq < 2; kq++)
      ap[kq] = *(const short8*)(QPs + qrow * 64 + ((kq * 4 + quad) ^ (qrow & 7)) * 8);

    // ---- O += P V  (B rows = Vt rows d = dn*16+l15, keys via chunk XOR) ----
    __builtin_amdgcn_s_setprio(1);
    #pragma unroll
    for (int dn = 0; dn < 4; dn++) {
      const int dr = dn * 16 + l15;
      #pragma unroll
      for (int kq = 0; kq < 2; kq++) {
        const short8 bv = *(const short8*)(Vrd + dr * 64 + ((kq * 4 + quad) ^ (dr & 7)) * 8);
        oacc[dn] = __builtin_amdgcn_mfma_f32_16x16x32_bf16(ap[kq], bv, oacc[dn], 0, 0, 0);
      }
    }
    __builtin_amdgcn_s_setprio(0);
  };

  for (int mt2 = 0; mt2 < 8; mt2 += 2) {
    {   // even step: compute (Ks0,Vt0); prefetch tile mt2+1 into (Ks1,Vt1)
      stageK(mt2 + 1, Ks1);
      uint4 n0 = *(const uint4*)(vsrc[0] + (size_t)(mt2 + 1) * TSTRIDE);
      uint4 n1 = *(const uint4*)(vsrc[1] + (size_t)(mt2 + 1) * TSTRIDE);
      tilecomp(mt2, Ks0, Vt0);
      scatterV(n0, n1, Vt1);
      __syncthreads();   // Ks1 DMA drained + Vt1 scatters visible
    }
    {   // odd step: compute (Ks1,Vt1); prefetch tile mt2+2 into (Ks0,Vt0)
      const bool more = (mt2 + 2) < 8;
      uint4 n0 = make_uint4(0, 0, 0, 0), n1 = make_uint4(0, 0, 0, 0);
      if (more) {
        stageK(mt2 + 2, Ks0);
        n0 = *(const uint4*)(vsrc[0] + (size_t)(mt2 + 2) * TSTRIDE);
        n1 = *(const uint4*)(vsrc[1] + (size_t)(mt2 + 2) * TSTRIDE);
      }
      tilecomp(mt2 + 1, Ks1, Vt1);
      if (more) scatterV(n0, n1, Vt0);
      __syncthreads();
    }
  }

  // epilogue: O rows q = quad*4+reg, cols d = dn*16+l15
  #pragma unroll
  for (int reg = 0; reg < 4; reg++) {
    const float inv = 1.f / runsum[reg];
    const int q = q0 + w * 16 + quad * 4 + reg;
    unsigned short* op = QKV + (size_t)(q * L_ + l) * 2304 + h * 64;
    #pragma unroll
    for (int dn = 0; dn < 4; dn++)
      op[dn * 16 + l15] = f2bf(oacc[dn][reg] * inv);
  }
}

// ---------------------------------------------------------------------------
__global__ __launch_bounds__(256) void score_kernel(const unsigned short* __restrict__ X,
                                                    const float* __restrict__ em,
                                                    float* __restrict__ Sv) {
  const int j = blockIdx.x;
  const int t = threadIdx.x;
  __shared__ float red[4];
  float part = 0.f;
  for (int c = 0; c < 3; c++) {
    const int d = t + c * 256;
    const unsigned short* p = X + (size_t)j * L_ * D_ + d;
    float s = 0.f;
    for (int l = 0; l < L_; l++) s += bf2f(p[l * D_]);
    const float diff = s * (1.f / 64.f) - em[j * D_ + d];
    part += diff * diff;
  }
  const float tot = blockSum256(part, red);
  if (t == 0) Sv[j] = tot;
}

// ---------------------------------------------------------------------------
__global__ __launch_bounds__(256) void finalize_kernel(const float* __restrict__ Sv,
                                                       int* __restrict__ mi,
                                                       float* __restrict__ out) {
  const int t = threadIdx.x;
  if (t < B_) {
    const int nr = mi[MI_NRESP + t];
    float best = 3.0e38f; int bi = 0;
    for (int j = 0; j < nr; j++) {
      const float v = Sv[j];
      if (v < best) { best = v; bi = j; }
    }
    mi[MI_NODE + t] = bi + 1;
    int next = nr / 20; if (next < 1) next = 1;
    out[OUT_NTL + t] = (float)(1 + next);
  }
  if (t == 0) out[OUT_NEA] = 0.f;
  __syncthreads();
  for (int idx = t; idx < B_ * T_; idx += 256) {
    const int b = idx >> 5, tt = idx & 31;
    out[OUT_OH + idx] = (tt == 0 || tt == mi[MI_NODE + b]) ? 1.f : 0.f;
  }
}

// ---------------------------------------------------------------------------
__global__ __launch_bounds__(256) void maskout_kernel(const float* __restrict__ am,
                                                      const int* __restrict__ mi,
                                                      float* __restrict__ out) {
  const int idx = blockIdx.x * 256 + threadIdx.x;
  const int b = idx >> 11, rem = idx & 2047;
  const int tt = rem >> 6, l = rem & 63;
  const int node = mi[MI_NODE + b];
  out[OUT_EXT + idx] = (tt == 0 || tt == node) ? 1.f : 0.f;
  float nm;
  if (tt == 0)      nm = am[(b * T_) * L_ + l];
  else if (tt == 1) nm = am[(b * T_ + node) * L_ + l];
  else              nm = 0.f;
  out[OUT_NMSK + idx] = nm;
}

// ---------------------------------------------------------------------------
__global__ __launch_bounds__(192) void newemb_kernel(const float* __restrict__ emb,
                                                     const int* __restrict__ mi,
                                                     float* __restrict__ out) {
  const int blk = blockIdx.x;
  const int b = blk >> 11, rem = blk & 2047;
  const int tt = rem >> 6, l = rem & 63;
  const int srct = (tt == 1) ? mi[MI_NODE + b] : 0;
  const float4 v = ((const float4*)(emb + (size_t)((b * T_ + srct) * L_ + l) * D_))[threadIdx.x];
  float* dst = out + OUT_NEMB + (size_t)blk * D_ + threadIdx.x * 4;
  dst[0] = v.x; dst[1] = v.y; dst[2] = v.z; dst[3] = v.w;
}

// ===========================================================================
extern "C" void kernel_launch(void* const* d_in, const int* in_sizes, int n_in,
                              void* d_out, int out_size, void* d_ws, size_t ws_size,
                              hipStream_t stream) {
  (void)in_sizes; (void)n_in; (void)out_size; (void)ws_size;
  const int*   tl  = (const int*)d_in[0];
  const float* emb = (const float*)d_in[1];
  const float* am  = (const float*)d_in[2];
  const float* P[28];
  for (int i = 0; i < 28; i++) P[i] = (const float*)d_in[3 + i];

  float* wsf   = (float*)d_ws;
  int*   mi    = (int*)d_ws;
  float* bias2 = wsf + WS_BIAS2;
  float* emean = wsf + WS_EMEAN;
  float* Sv    = wsf + WS_S;
  unsigned short* Wst = (unsigned short*)(wsf + WS_WST);  // peW | pdW
  unsigned short* peW = Wst;
  unsigned short* pdW = Wst + 196608;
  float* peB   = wsf + PEB_F;
  unsigned short* BIG = (unsigned short*)(wsf + WS_BIG);
  unsigned short* Zs  = (unsigned short*)(wsf + WS_BIG);  // bf16 Z overlay
  float* out   = (float*)d_out;
  unsigned short* X    = (unsigned short*)(out + OUT_XSCR);   // bf16 residual
  unsigned short* WSTK = (unsigned short*)(out + OUT_WSTK);   // converted weights

  meta_kernel<<<1, 64, 0, stream>>>(tl, mi);
  // convert all layer weights up front (4 passes)
  for (int p = 0; p < 4; p++) {
    const float* const* q = P + (p >> 1) * 12;
    const int i = p & 1;
    w2bf4_kernel<<<WPASS / 1024, 256, 0, stream>>>(
        q[0] + (size_t)i * 3 * D_ * D_, q[2] + (size_t)i * D_ * D_,
        q[6] + (size_t)i * F_ * D_, q[8] + (size_t)i * D_ * F_,
        WSTK + (size_t)p * WPASS);
  }
  pepd_stage<<<385, 256, 0, stream>>>(P[24], P[25], P[26], peW, pdW, peB);
  gather_kernel<<<NP_ * L_, 192, 0, stream>>>(emb, am, mi, X, bias2);
  emean_kernel<<<NP_, 256, 0, stream>>>(X, emean);
  zerotail_kernel<<<NP_ * L_, 256, 0, stream>>>(mi, BIG);

  const int RT2 = NP_ * 64 / 256;   // 128 row tiles
  for (int s = 0; s < 2; s++) {
    const float* const* q = P + s * 12;
    for (int i = 0; i < 2; i++) {
      const unsigned short* WP = WSTK + (size_t)(s * 2 + i) * WPASS;
      // QKV: X -> BIG [rows, 2304]
      gemm_mfma<0, false><<<RT2 * 9, 512, 0, stream>>>(
          X, D_, D_, WP, D_, q[1] + i * 3 * D_, BIG, 3 * D_, 9, mi);
      attn_kernel<<<dim3(L_ * H_, 8), 256, 0, stream>>>(BIG, bias2, mi);
      // out-proj: O (Q cols of BIG, lda=2304) -> += X
      gemm_mfma<0, true><<<RT2 * 3, 512, 0, stream>>>(
          BIG, 3 * D_, D_, WP + WSEG0, D_, q[3] + i * D_, X, D_, 3, mi);
      ln_kernel<<<NP_ * L_, 256, 0, stream>>>(X, q[4] + i * D_, q[5] + i * D_, mi);
      // FFN1: X -> hidden BIG [rows, 2048] (relu)
      gemm_mfma<1, false><<<RT2 * 8, 512, 0, stream>>>(
          X, D_, D_, WP + WSEG0 + WSEG1, D_, q[7] + i * F_, BIG, F_, 8, mi);
      // FFN2: hidden -> += X
      gemm_mfma<0, true><<<RT2 * 3, 512, 0, stream>>>(
          BIG, F_, F_, WP + WSEG0 + WSEG1 + WSEG2, F_, q[9] + i * D_, X, D_, 3, mi);
      ln_kernel<<<NP_ * L_, 256, 0, stream>>>(X, q[10] + i * D_, q[11] + i * D_, mi);
    }
    if (s == 0) {
      // z = tanh(h @ pe_w^T + pe_b) -> Zs bf16 [rows][256] (cols 100..255 = 0)
      gemm_mfma<2, false><<<RT2 * 1, 512, 0, stream>>>(
          X, D_, D_, peW, D_, peB, Zs, 256, 1, mi);
      // zd = tanh(z @ pd_w^T + pd_b) -> X bf16 (decoder input)
      gemm_mfma<2, false><<<RT2 * 3, 512, 0, stream>>>(
          Zs, 256, 256, pdW, 256, P[27], X, D_, 3, mi);
    }
  }

  score_kernel<<<NP_, 256, 0, stream>>>(X, emean, Sv);
  finalize_kernel<<<1, 256, 0, stream>>>(Sv, mi, out);
  maskout_kernel<<<128, 256, 0, stream>>>(am, mi, out);
  newemb_kernel<<<B_ * T_ * L_, 192, 0, stream>>>(emb, mi, out);
}

// Round 7
// 2843.902 us; speedup vs baseline: 1.0970x; 1.0618x over previous
//
#include <hip/hip_runtime.h>
#include <hip/hip_bf16.h>
#include <math.h>

// ============================================================================
// ResponseFilter — round 9: balanced active-tile XCD swizzle + 2-Qtile attn.
//
// Round-8 post-mortem: chunked XCD swizzle over the PADDED grid handed XCDs
// 6-7 only empty row-tiles (rows ~23000 of 32768) -> 2/8 XCDs idle, locality
// gain cancelled. Fix: compute active tile count NTa = ceil(rows/256)*CT on
// device, early-exit id >= NTa, bijective m204 chunk mapping over NTa only.
// attn: 512 threads / 8 waves, each block owns TWO Q-tiles (grid (768,4)) ->
// K/V HBM traffic halves, per-staged-byte compute doubles. Mechanical
// widening of the round-5-proven kernel (same per-wave math and swizzles):
// QPs 128 rows (16 KB), K staged 1 chunk/thread, V 1 uint4/thread (d-group =
// wave), Bls 1 elem/thread. LDS 50 KB -> 2-3 blocks/CU.
// ============================================================================

#define B_  16
#define T_  32
#define L_  64
#define D_  768
#define H_  12
#define F_  2048
#define ZR_ 100
#define NP_ 512
#define EPS_ 1e-5f

// meta int offsets (d_ws as int*)
#define MI_NTOT  0
#define MI_NRESP 8
#define MI_OFF   32
#define MI_BIDX  64
#define MI_TIDX  576
#define MI_NODE  1088

// ws float offsets
#define WS_BIAS2 2048
#define WS_EMEAN 34816
#define WS_S     428032
#define WS_WST   428544    // pe/pd padded bf16 weights + padded pe bias
#define WS_BIG   1313280   // bf16 QKV/hidden region; bf16 Z overlay

#define PEB_F    (WS_WST + 196608)   // float offset of padded pe bias [256]

// d_out float offsets (flat tuple: oh[512], ext_mask[32768], n_ext_adv[1],
// new_tree_lens[16], new_emb[25165824], new_msk[32768])
#define OUT_OH   0
#define OUT_EXT  512
#define OUT_NEA  33280
#define OUT_NTL  33281
#define OUT_NEMB 33297
#define OUT_NMSK 25199121
#define OUT_XSCR 33300      // bf16 X scratch, 32768*768 ushorts (ends 12616212)
#define OUT_WSTK 12616224   // bf16 converted weights, 4 passes x 5,505,024 ushorts

// per-pass converted-weight segment sizes (ushorts)
#define WSEG0 1769472   // qkv  [2304][768]
#define WSEG1 589824    // out  [768][768]
#define WSEG2 1572864   // w1   [2048][768]
#define WSEG3 1572864   // w2   [768][2048]
#define WPASS 5505024

typedef __attribute__((ext_vector_type(8))) short short8;
typedef __attribute__((ext_vector_type(4))) float f32x4;

__device__ inline float bf2f(unsigned s) {
  return __uint_as_float((s & 0xffffu) << 16);
}
__device__ inline unsigned short f2bf(float x) {
  unsigned u = __float_as_uint(x);
  u += 0x7fffu + ((u >> 16) & 1u);      // round-to-nearest-even
  return (unsigned short)(u >> 16);
}
__device__ inline unsigned pack2(float a, float b) {
  return (unsigned)f2bf(a) | ((unsigned)f2bf(b) << 16);
}

// ---------------------------------------------------------------------------
__global__ void meta_kernel(const int* __restrict__ tl, int* __restrict__ mi) {
  if (threadIdx.x != 0) return;
  int off = 0;
  for (int b = 0; b < B_; b++) {
    int nr = tl[b] - 1;
    mi[MI_NRESP + b] = nr;
    mi[MI_OFF + b] = off;
    off += nr;
  }
  mi[MI_NTOT] = off;
  for (int j = 0; j < NP_; j++) {
    int b = -1, t = 0;
    if (j < off) {
      b = 0;
      while (b + 1 < B_ && j >= mi[MI_OFF + b + 1]) b++;
      t = j - mi[MI_OFF + b] + 1;
    }
    mi[MI_BIDX + j] = b;
    mi[MI_TIDX + j] = t;
  }
}

// ---------------------------------------------------------------------------
// batched fp32 -> bf16 conversion of one layer-pass's 4 weight matrices.
// grid = WPASS/1024 blocks; segment boundaries are multiples of 1024.
__global__ __launch_bounds__(256) void w2bf4_kernel(
    const float* __restrict__ s0, const float* __restrict__ s1,
    const float* __restrict__ s2, const float* __restrict__ s3,
    unsigned short* __restrict__ dst) {
  const int e = blockIdx.x * 1024 + threadIdx.x * 4;
  const float* src;
  int off;
  if (e < WSEG0)                         { src = s0; off = e; }
  else if (e < WSEG0 + WSEG1)            { src = s1; off = e - WSEG0; }
  else if (e < WSEG0 + WSEG1 + WSEG2)    { src = s2; off = e - WSEG0 - WSEG1; }
  else                                   { src = s3; off = e - WSEG0 - WSEG1 - WSEG2; }
  float4 v = *(const float4*)(src + off);
  uint2 pk; pk.x = pack2(v.x, v.y); pk.y = pack2(v.z, v.w);
  *(uint2*)(dst + e) = pk;
}

// ---------------------------------------------------------------------------
// pe_w [100][768] -> peW [256][768] bf16 (rows >=100 zero)
// pd_w [768][100] -> pdW [768][256] bf16 (cols >=100 zero)
// pe_b [100]      -> peB [256] fp32 (zero-padded)
__global__ __launch_bounds__(256) void pepd_stage(
    const float* __restrict__ pew, const float* __restrict__ peb,
    const float* __restrict__ pdw,
    unsigned short* __restrict__ dpe, unsigned short* __restrict__ dpd,
    float* __restrict__ dpeb) {
  const int blk = blockIdx.x, t = threadIdx.x;
  if (blk < 192) {                       // pe: 196608 elems
    const int e = blk * 1024 + t * 4;
    const int r = e / 768, c = e % 768;
    float v[4];
    #pragma unroll
    for (int j = 0; j < 4; j++) v[j] = (r < ZR_) ? pew[r * 768 + c + j] : 0.f;
    uint2 pk; pk.x = pack2(v[0], v[1]); pk.y = pack2(v[2], v[3]);
    *(uint2*)(dpe + e) = pk;
  } else if (blk < 384) {                // pd: 196608 elems
    const int e = (blk - 192) * 1024 + t * 4;
    const int r = e / 256, c = e % 256;
    float v[4];
    #pragma unroll
    for (int j = 0; j < 4; j++) v[j] = (c + j < ZR_) ? pdw[r * ZR_ + c + j] : 0.f;
    uint2 pk; pk.x = pack2(v[0], v[1]); pk.y = pack2(v[2], v[3]);
    *(uint2*)(dpd + e) = pk;
  } else {                               // bias pad
    dpeb[t] = (t < ZR_) ? peb[t] : 0.f;
  }
}

// ---------------------------------------------------------------------------
// X[j,l,:] bf16 = reply embedding (zero for padded j); bias2 = mask or -1e30
__global__ __launch_bounds__(192) void gather_kernel(
    const float* __restrict__ emb, const float* __restrict__ am,
    const int* __restrict__ mi, unsigned short* __restrict__ X,
    float* __restrict__ bias2) {
  const int blk = blockIdx.x;          // j*64 + l
  const int j = blk >> 6, l = blk & 63;
  const int ntot = mi[MI_NTOT];
  const int t = threadIdx.x;
  float4 v = make_float4(0.f, 0.f, 0.f, 0.f);
  if (j < ntot) {
    const int b = mi[MI_BIDX + j], tt = mi[MI_TIDX + j];
    v = ((const float4*)(emb + (size_t)((b * T_ + tt) * L_ + l) * D_))[t];
    if (t == 0) bias2[blk] = am[(b * T_ + tt) * L_ + l];
  } else {
    if (t == 0) bias2[blk] = -1e30f;
  }
  uint2 pk; pk.x = pack2(v.x, v.y); pk.y = pack2(v.z, v.w);
  *(uint2*)(X + (size_t)blk * D_ + t * 4) = pk;
}

// ---------------------------------------------------------------------------
// zero QKV rows >= ntot*64 in BIG (once per launch): attention reads K/V for
// all 512 padded responses; rows beyond the last GEMM tile must be finite.
__global__ __launch_bounds__(256) void zerotail_kernel(const int* __restrict__ mi,
                                                       unsigned short* __restrict__ BIG) {
  const int row = blockIdx.x;                 // 0 .. 32767
  if (row < mi[MI_NTOT] * 64) return;
  uint4 z = make_uint4(0u, 0u, 0u, 0u);
  uint4* p = (uint4*)(BIG + (size_t)row * 2304);   // 2304 ushorts = 288 uint4
  for (int c = threadIdx.x; c < 288; c += 256) p[c] = z;
}

// ---------------------------------------------------------------------------
__global__ __launch_bounds__(256) void emean_kernel(const unsigned short* __restrict__ X,
                                                    float* __restrict__ em) {
  const int j = blockIdx.x;
  int d = threadIdx.x;
  for (int c = 0; c < 3; c++, d += 256) {
    const unsigned short* p = X + (size_t)j * L_ * D_ + d;
    float s = 0.f;
    for (int l = 0; l < L_; l++) s += bf2f(p[l * D_]);
    em[j * D_ + d] = s * (1.f / 64.f);
  }
}

// ---------------------------------------------------------------------------
__device__ inline float blockSum256(float v, float* red) {
  #pragma unroll
  for (int o = 32; o > 0; o >>= 1) v += __shfl_down(v, o);
  const int lane = threadIdx.x & 63, wid = threadIdx.x >> 6;
  __syncthreads();
  if (lane == 0) red[wid] = v;
  __syncthreads();
  return red[0] + red[1] + red[2] + red[3];
}

// in-place LN (bf16 storage, fp32 stats); skips padded rows
__global__ __launch_bounds__(256) void ln_kernel(unsigned short* __restrict__ X,
                                                 const float* __restrict__ g,
                                                 const float* __restrict__ bb,
                                                 const int* __restrict__ mi) {
  const int row = blockIdx.x;
  if (row >= mi[MI_NTOT] * L_) return;
  unsigned short* p = X + (size_t)row * D_;
  const int t = threadIdx.x;
  __shared__ float red[4];
  float v0 = bf2f(p[t]), v1 = bf2f(p[t + 256]), v2 = bf2f(p[t + 512]);
  float s = blockSum256(v0 + v1 + v2, red);
  float m = s * (1.f / 768.f);
  float d0 = v0 - m, d1 = v1 - m, d2 = v2 - m;
  float q = blockSum256(d0 * d0 + d1 * d1 + d2 * d2, red);
  float r = rsqrtf(q * (1.f / 768.f) + EPS_);
  p[t]       = f2bf(d0 * r * g[t]       + bb[t]);
  p[t + 256] = f2bf(d1 * r * g[t + 256] + bb[t + 256]);
  p[t + 512] = f2bf(d2 * r * g[t + 512] + bb[t + 512]);
}

// ---------------------------------------------------------------------------
// MFMA bf16 GEMM: C[M,N] = [C +] act(A @ W^T + bias). 256x256 tile, 512 thr
// (8 waves 2Mx4N; wave = 128x64 via 8x4 of 16x16x32 MFMA), BK=64 dbuf.
// Launch grid 128*CT (static); ACTIVE tiles NTa = ceil(rows/256)*CT computed
// on device; id >= NTa exits; bijective m204 chunk map over NTa (8 XCDs),
// col-fastest within chunk -> balanced AND A-panel-local.
// LDS rows 64 ushorts (128B = bank wrap): group g of row at slot g^(row&7).
// Staging for kt+1 interleaved between the 4 MFMA clusters of kt (round-6).
// ACT: 0 none, 1 relu, 2 tanh.
template <int ACT, bool ADD>
__global__ __launch_bounds__(512, 2) void gemm_mfma(
    const unsigned short* __restrict__ A, int lda, int K,
    const unsigned short* __restrict__ W, int ldw,
    const float* __restrict__ bias,
    unsigned short* __restrict__ C, int ldc, int CT,
    const int* __restrict__ mi) {
  const int rows = mi[MI_NTOT] * 64;
  const int RTa = (rows + 255) >> 8;
  const int NTa = RTa * CT;
  const int id = blockIdx.x;
  if (id >= NTa) return;
  // bijective XCD chunk map (m204): xcd k gets a contiguous wg range
  const int q8 = NTa >> 3, r8 = NTa & 7;
  const int xcd = id & 7, idx = id >> 3;
  const int wg = (xcd < r8 ? xcd * (q8 + 1) : r8 * (q8 + 1) + (xcd - r8) * q8) + idx;
  const int row0 = (wg / CT) * 256;
  const int col0 = (wg % CT) * 256;
  __shared__ unsigned short As[2][256 * 64];
  __shared__ unsigned short Bs[2][256 * 64];
  const int t = threadIdx.x;            // 0..511
  const int lane = t & 63, w = t >> 6;  // 8 waves
  const int wr = w >> 2, wc = w & 3;    // 2 x 4 wave grid
  const int quad = lane >> 4, l15 = lane & 15;

  // staging coords: thread t handles chunk c = ph*512 + t (ph = 0..3);
  // row = ph*64 + (t>>3), g = t&7; source group gs = g ^ (row&7).
  const int srow = t >> 3;              // 0..63
  const int sgs = (t & 7) ^ (srow & 7);
  const unsigned short* aSrc = A + (size_t)(row0 + srow) * lda + sgs * 8;
  const unsigned short* bSrc = W + (size_t)(col0 + srow) * ldw + sgs * 8;

#define STAGE_(ph, kk, Ad, Bd)                                                  \
  do {                                                                          \
    __builtin_amdgcn_global_load_lds(                                           \
        (const __attribute__((address_space(1))) void*)(aSrc + (size_t)(ph) * 64 * lda + (kk)), \
        (__attribute__((address_space(3))) void*)((Ad) + (ph) * 4096 + w * 512), 16, 0, 0); \
    __builtin_amdgcn_global_load_lds(                                           \
        (const __attribute__((address_space(1))) void*)(bSrc + (size_t)(ph) * 64 * ldw + (kk)), \
        (__attribute__((address_space(3))) void*)((Bd) + (ph) * 4096 + w * 512), 16, 0, 0); \
  } while (0)

  auto LDA_ = [&](const unsigned short* buf, int m, int ks) -> short8 {
    const int ar = wr * 128 + m * 16 + l15;
    return *(const short8*)(buf + ar * 64 + (((ks << 2) + quad) ^ (ar & 7)) * 8);
  };
  auto LDB_ = [&](const unsigned short* buf, int n, int ks) -> short8 {
    const int bn = wc * 64 + n * 16 + l15;
    return *(const short8*)(buf + bn * 64 + (((ks << 2) + quad) ^ (bn & 7)) * 8);
  };

  f32x4 acc[8][4];
  #pragma unroll
  for (int m = 0; m < 8; m++)
    #pragma unroll
    for (int n = 0; n < 4; n++) acc[m][n] = (f32x4){0.f, 0.f, 0.f, 0.f};

  // prologue: stage tile 0
  STAGE_(0, 0, As[0], Bs[0]);
  STAGE_(1, 0, As[0], Bs[0]);
  STAGE_(2, 0, As[0], Bs[0]);
  STAGE_(3, 0, As[0], Bs[0]);
  __syncthreads();

  const int KT = K >> 6;
  for (int kt = 0; kt < KT; ++kt) {
    const unsigned short* Ac = As[kt & 1];
    const unsigned short* Bc = Bs[kt & 1];
    unsigned short* An = As[(kt + 1) & 1];
    unsigned short* Bn = Bs[(kt + 1) & 1];
    const int kn = (kt + 1) << 6;
    const bool more = kn < K;
    short8 afr[4], bfr[4];

    // ---- cluster 1: m 0-3, ks 0 ----
    #pragma unroll
    for (int n = 0; n < 4; n++) bfr[n] = LDB_(Bc, n, 0);
    #pragma unroll
    for (int m = 0; m < 4; m++) afr[m] = LDA_(Ac, m, 0);
    if (more) STAGE_(0, kn, An, Bn);
    __builtin_amdgcn_s_setprio(1);
    #pragma unroll
    for (int m = 0; m < 4; m++)
      #pragma unroll
      for (int n = 0; n < 4; n++)
        acc[m][n] = __builtin_amdgcn_mfma_f32_16x16x32_bf16(afr[m], bfr[n], acc[m][n], 0, 0, 0);
    __builtin_amdgcn_s_setprio(0);

    // ---- cluster 2: m 4-7, ks 0 (B frags reused) ----
    #pragma unroll
    for (int m = 0; m < 4; m++) afr[m] = LDA_(Ac, m + 4, 0);
    if (more) STAGE_(1, kn, An, Bn);
    __builtin_amdgcn_s_setprio(1);
    #pragma unroll
    for (int m = 0; m < 4; m++)
      #pragma unroll
      for (int n = 0; n < 4; n++)
        acc[m + 4][n] = __builtin_amdgcn_mfma_f32_16x16x32_bf16(afr[m], bfr[n], acc[m + 4][n], 0, 0, 0);
    __builtin_amdgcn_s_setprio(0);

    // ---- cluster 3: m 0-3, ks 1 ----
    #pragma unroll
    for (int n = 0; n < 4; n++) bfr[n] = LDB_(Bc, n, 1);
    #pragma unroll
    for (int m = 0; m < 4; m++) afr[m] = LDA_(Ac, m, 1);
    if (more) STAGE_(2, kn, An, Bn);
    __builtin_amdgcn_s_setprio(1);
    #pragma unroll
    for (int m = 0; m < 4; m++)
      #pragma unroll
      for (int n = 0; n < 4; n++)
        acc[m][n] = __builtin_amdgcn_mfma_f32_16x16x32_bf16(afr[m], bfr[n], acc[m][n], 0, 0, 0);
    __builtin_amdgcn_s_setprio(0);

    // ---- cluster 4: m 4-7, ks 1 ----
    #pragma unroll
    for (int m = 0; m < 4; m++) afr[m] = LDA_(Ac, m + 4, 1);
    if (more) STAGE_(3, kn, An, Bn);
    __builtin_amdgcn_s_setprio(1);
    #pragma unroll
    for (int m = 0; m < 4; m++)
      #pragma unroll
      for (int n = 0; n < 4; n++)
        acc[m + 4][n] = __builtin_amdgcn_mfma_f32_16x16x32_bf16(afr[m], bfr[n], acc[m + 4][n], 0, 0, 0);
    __builtin_amdgcn_s_setprio(0);

    __syncthreads();   // drains kt+1 staging (issued early) + swap
  }
#undef STAGE_

  // epilogue: C/D layout col = lane&15, row = quad*4 + reg
  float bv[4];
  #pragma unroll
  for (int n = 0; n < 4; n++) bv[n] = bias[col0 + wc * 64 + n * 16 + l15];
  #pragma unroll
  for (int m = 0; m < 8; m++) {
    #pragma unroll
    for (int reg = 0; reg < 4; reg++) {
      const size_t cr = (size_t)(row0 + wr * 128 + m * 16 + quad * 4 + reg) * ldc;
      #pragma unroll
      for (int n = 0; n < 4; n++) {
        const int cn = col0 + wc * 64 + n * 16 + l15;
        float x = acc[m][n][reg] + bv[n];
        if (ACT == 1) x = fmaxf(x, 0.f);
        if (ACT == 2) x = tanhf(x);
        if (ADD) x += bf2f(C[cr + cn]);
        C[cr + cn] = f2bf(x);
      }
    }
  }
}

// ---------------------------------------------------------------------------
// Pipelined MFMA flash attention per (l,h) [blockIdx.x] x ntp [blockIdx.y].
// 512 threads / 8 waves; block owns TWO Q-tiles (128 q rows: ntp*128 ..);
// wave w owns q rows w*16..w*16+15. K double-buffered via global_load_lds
// (1 chunk/thread); V double-buffered via reg-staging (1 uint4/thread,
// d-group = wave id, scatter-late). ONE __syncthreads per key tile.
__global__ __launch_bounds__(512) void attn_kernel(
    unsigned short* __restrict__ QKV, const float* __restrict__ bias2,
    const int* __restrict__ mi) {
  const int ntot = mi[MI_NTOT];
  const int lh = blockIdx.x, ntp = blockIdx.y;
  if (ntp * 128 >= ntot) return;
  const int l = lh / H_, h = lh - l * H_;
  __shared__ unsigned short QPs[128 * 64];  // Q staging, then P (per-wave rows)
  __shared__ unsigned short Ks0[64 * 64], Ks1[64 * 64];
  __shared__ unsigned short Vt0[64 * 64], Vt1[64 * 64];  // V^T [d][key], swizzled
  __shared__ float Bls[512];
  const int t = threadIdx.x;
  const int lane = t & 63, w = t >> 6;      // 8 waves
  const int quad = lane >> 4, l15 = lane & 15;
  const int q0 = ntp * 128;
  const size_t TSTRIDE = (size_t)64 * L_ * 2304;   // elems per 64-key tile

  // K source (1 chunk/thread): row = t>>3 in [0,64), group swizzled
  const int krow = t >> 3;
  const int kgs = (t & 7) ^ (krow & 7);
  const unsigned short* ksrc =
      QKV + (size_t)(krow * L_ + l) * 2304 + 768 + h * 64 + kgs * 8;
  // V source (1 uint4/thread): d-group = w, key = lane
  const unsigned short* vsrc =
      QKV + (size_t)(lane * L_ + l) * 2304 + 1536 + h * 64 + w * 8;

  auto stageK = [&](int mt, unsigned short* Kw) {
    __builtin_amdgcn_global_load_lds(
        (const __attribute__((address_space(1))) void*)(ksrc + (size_t)mt * TSTRIDE),
        (__attribute__((address_space(3))) void*)(Kw + w * 512), 16, 0, 0);
  };
  auto scatterV = [&](uint4 a0, unsigned short* Vw) {
    const unsigned short* p0 = (const unsigned short*)&a0;
    #pragma unroll
    for (int j = 0; j < 8; j++) {
      const int d = w * 8 + j;
      Vw[d * 64 + ((lane >> 3) ^ (d & 7)) * 8 + (lane & 7)] = p0[j];
    }
  };

  // prologue: stage Q (2 chunks/thread) + K0, V0 -> regs, bias -> LDS
  #pragma unroll
  for (int r = 0; r < 2; r++) {
    const int c = r * 512 + t;
    const int row = c >> 3, g = c & 7, gs = g ^ (row & 7);
    const unsigned short* gq =
        QKV + (size_t)((q0 + row) * L_ + l) * 2304 + h * 64 + gs * 8;
    __builtin_amdgcn_global_load_lds(
        (const __attribute__((address_space(1))) void*)gq,
        (__attribute__((address_space(3))) void*)(QPs + r * 4096 + w * 512), 16, 0, 0);
  }
  stageK(0, Ks0);
  uint4 pv0 = *(const uint4*)vsrc;
  Bls[t] = bias2[t * 64 + l];
  __syncthreads();                       // Q,K0 in LDS; pv0 in regs

  // Q fragments (loop-invariant): A-operand row = l15 within wave's 16 rows
  const int qrow = w * 16 + l15;         // 0..127
  short8 aq[2];
  #pragma unroll
  for (int kq = 0; kq < 2; kq++)
    aq[kq] = *(const short8*)(QPs + qrow * 64 + ((kq * 4 + quad) ^ (qrow & 7)) * 8);
  scatterV(pv0, Vt0);
  __syncthreads();                       // Vt0 visible; aq read before P reuse

  float runmax[4], runsum[4];
  f32x4 oacc[4];
  #pragma unroll
  for (int i = 0; i < 4; i++) {
    runmax[i] = -3.0e38f; runsum[i] = 0.f;
    oacc[i] = (f32x4){0.f, 0.f, 0.f, 0.f};
  }

  auto tilecomp = [&](int mt, const unsigned short* Krd, const unsigned short* Vrd) {
    // ---- S = Q K^T ----
    f32x4 sa[4];
    #pragma unroll
    for (int n = 0; n < 4; n++) sa[n] = (f32x4){0.f, 0.f, 0.f, 0.f};
    __builtin_amdgcn_s_setprio(1);
    #pragma unroll
    for (int n = 0; n < 4; n++) {
      const int kr = n * 16 + l15;
      #pragma unroll
      for (int kq = 0; kq < 2; kq++) {
        const short8 bk = *(const short8*)(Krd + kr * 64 + ((kq * 4 + quad) ^ (kr & 7)) * 8);
        sa[n] = __builtin_amdgcn_mfma_f32_16x16x32_bf16(aq[kq], bk, sa[n], 0, 0, 0);
      }
    }
    __builtin_amdgcn_s_setprio(0);
    float bj[4];
    #pragma unroll
    for (int n = 0; n < 4; n++) bj[n] = Bls[mt * 64 + n * 16 + l15];
    #pragma unroll
    for (int n = 0; n < 4; n++)
      #pragma unroll
      for (int reg = 0; reg < 4; reg++)
        sa[n][reg] = sa[n][reg] * 0.125f + bj[n];

    // ---- online softmax (rows q = quad*4+reg; reduce over 16-lane group) ----
    float rmax[4], psum[4];
    #pragma unroll
    for (int reg = 0; reg < 4; reg++)
      rmax[reg] = fmaxf(fmaxf(sa[0][reg], sa[1][reg]), fmaxf(sa[2][reg], sa[3][reg]));
    #pragma unroll
    for (int o = 1; o < 16; o <<= 1)
      #pragma unroll
      for (int reg = 0; reg < 4; reg++)
        rmax[reg] = fmaxf(rmax[reg], __shfl_xor(rmax[reg], o));
    #pragma unroll
    for (int reg = 0; reg < 4; reg++) {
      const float nm = fmaxf(runmax[reg], rmax[reg]);
      const float alpha = __expf(runmax[reg] - nm);
      runmax[reg] = nm;
      float s0 = 0.f;
      #pragma unroll
      for (int n = 0; n < 4; n++) {
        const float p = __expf(sa[n][reg] - nm);
        sa[n][reg] = p; s0 += p;
      }
      psum[reg] = s0;
      runsum[reg] *= alpha;
      #pragma unroll
      for (int dn = 0; dn < 4; dn++) oacc[dn][reg] *= alpha;
    }
    #pragma unroll
    for (int o = 1; o < 16; o <<= 1)
      #pragma unroll
      for (int reg = 0; reg < 4; reg++) psum[reg] += __shfl_xor(psum[reg], o);
    #pragma unroll
    for (int reg = 0; reg < 4; reg++) runsum[reg] += psum[reg];

    // ---- P -> LDS bf16 (wave-private rows; in-wave DS order suffices) ----
    #pragma unroll
    for (int n = 0; n < 4; n++) {
      const int key = n * 16 + l15;
      #pragma unroll
      for (int reg = 0; reg < 4; reg++) {
        const int qr = w * 16 + quad * 4 + reg;
        QPs[qr * 64 + ((key >> 3) ^ (qr & 7)) * 8 + (key & 7)] = f2bf(sa[n][reg]);
      }
    }
    short8 ap[2];
    #pragma unroll
    for (int kq = 0; kq < 2; kq++)
      ap[kq] = *(const short8*)(QPs + qrow * 64 + ((kq * 4 + quad) ^ (qrow & 7)) * 8);

    // ---- O += P V  (B rows = Vt rows d = dn*16+l15, keys via chunk XOR) ----
    __builtin_amdgcn_s_setprio(1);
    #pragma unroll
    for (int dn = 0; dn < 4; dn++) {
      const int dr = dn * 16 + l15;
      #pragma unroll
      for (int kq = 0; kq < 2; kq++) {
        const short8 bv = *(const short8*)(Vrd + dr * 64 + ((kq * 4 + quad) ^ (dr & 7)) * 8);
        oacc[dn] = __builtin_amdgcn_mfma_f32_16x16x32_bf16(ap[kq], bv, oacc[dn], 0, 0, 0);
      }
    }
    __builtin_amdgcn_s_setprio(0);
  };

  for (int mt2 = 0; mt2 < 8; mt2 += 2) {
    {   // even step: compute (Ks0,Vt0); prefetch tile mt2+1 into (Ks1,Vt1)
      stageK(mt2 + 1, Ks1);
      uint4 n0 = *(const uint4*)(vsrc + (size_t)(mt2 + 1) * TSTRIDE);
      tilecomp(mt2, Ks0, Vt0);
      scatterV(n0, Vt1);
      __syncthreads();   // Ks1 DMA drained + Vt1 scatters visible
    }
    {   // odd step: compute (Ks1,Vt1); prefetch tile mt2+2 into (Ks0,Vt0)
      const bool more = (mt2 + 2) < 8;
      uint4 m0 = make_uint4(0, 0, 0, 0);
      if (more) {
        stageK(mt2 + 2, Ks0);
        m0 = *(const uint4*)(vsrc + (size_t)(mt2 + 2) * TSTRIDE);
      }
      tilecomp(mt2 + 1, Ks1, Vt1);
      if (more) scatterV(m0, Vt0);
      __syncthreads();
    }
  }

  // epilogue: O rows q = quad*4+reg, cols d = dn*16+l15
  #pragma unroll
  for (int reg = 0; reg < 4; reg++) {
    const float inv = 1.f / runsum[reg];
    const int q = q0 + w * 16 + quad * 4 + reg;
    unsigned short* op = QKV + (size_t)(q * L_ + l) * 2304 + h * 64;
    #pragma unroll
    for (int dn = 0; dn < 4; dn++)
      op[dn * 16 + l15] = f2bf(oacc[dn][reg] * inv);
  }
}

// ---------------------------------------------------------------------------
__global__ __launch_bounds__(256) void score_kernel(const unsigned short* __restrict__ X,
                                                    const float* __restrict__ em,
                                                    float* __restrict__ Sv) {
  const int j = blockIdx.x;
  const int t = threadIdx.x;
  __shared__ float red[4];
  float part = 0.f;
  for (int c = 0; c < 3; c++) {
    const int d = t + c * 256;
    const unsigned short* p = X + (size_t)j * L_ * D_ + d;
    float s = 0.f;
    for (int l = 0; l < L_; l++) s += bf2f(p[l * D_]);
    const float diff = s * (1.f / 64.f) - em[j * D_ + d];
    part += diff * diff;
  }
  const float tot = blockSum256(part, red);
  if (t == 0) Sv[j] = tot;
}

// ---------------------------------------------------------------------------
__global__ __launch_bounds__(256) void finalize_kernel(const float* __restrict__ Sv,
                                                       int* __restrict__ mi,
                                                       float* __restrict__ out) {
  const int t = threadIdx.x;
  if (t < B_) {
    const int nr = mi[MI_NRESP + t];
    float best = 3.0e38f; int bi = 0;
    for (int j = 0; j < nr; j++) {
      const float v = Sv[j];
      if (v < best) { best = v; bi = j; }
    }
    mi[MI_NODE + t] = bi + 1;
    int next = nr / 20; if (next < 1) next = 1;
    out[OUT_NTL + t] = (float)(1 + next);
  }
  if (t == 0) out[OUT_NEA] = 0.f;
  __syncthreads();
  for (int idx = t; idx < B_ * T_; idx += 256) {
    const int b = idx >> 5, tt = idx & 31;
    out[OUT_OH + idx] = (tt == 0 || tt == mi[MI_NODE + b]) ? 1.f : 0.f;
  }
}

// ---------------------------------------------------------------------------
__global__ __launch_bounds__(256) void maskout_kernel(const float* __restrict__ am,
                                                      const int* __restrict__ mi,
                                                      float* __restrict__ out) {
  const int idx = blockIdx.x * 256 + threadIdx.x;
  const int b = idx >> 11, rem = idx & 2047;
  const int tt = rem >> 6, l = rem & 63;
  const int node = mi[MI_NODE + b];
  out[OUT_EXT + idx] = (tt == 0 || tt == node) ? 1.f : 0.f;
  float nm;
  if (tt == 0)      nm = am[(b * T_) * L_ + l];
  else if (tt == 1) nm = am[(b * T_ + node) * L_ + l];
  else              nm = 0.f;
  out[OUT_NMSK + idx] = nm;
}

// ---------------------------------------------------------------------------
__global__ __launch_bounds__(192) void newemb_kernel(const float* __restrict__ emb,
                                                     const int* __restrict__ mi,
                                                     float* __restrict__ out) {
  const int blk = blockIdx.x;
  const int b = blk >> 11, rem = blk & 2047;
  const int tt = rem >> 6, l = rem & 63;
  const int srct = (tt == 1) ? mi[MI_NODE + b] : 0;
  const float4 v = ((const float4*)(emb + (size_t)((b * T_ + srct) * L_ + l) * D_))[threadIdx.x];
  float* dst = out + OUT_NEMB + (size_t)blk * D_ + threadIdx.x * 4;
  dst[0] = v.x; dst[1] = v.y; dst[2] = v.z; dst[3] = v.w;
}

// ===========================================================================
extern "C" void kernel_launch(void* const* d_in, const int* in_sizes, int n_in,
                              void* d_out, int out_size, void* d_ws, size_t ws_size,
                              hipStream_t stream) {
  (void)in_sizes; (void)n_in; (void)out_size; (void)ws_size;
  const int*   tl  = (const int*)d_in[0];
  const float* emb = (const float*)d_in[1];
  const float* am  = (const float*)d_in[2];
  const float* P[28];
  for (int i = 0; i < 28; i++) P[i] = (const float*)d_in[3 + i];

  float* wsf   = (float*)d_ws;
  int*   mi    = (int*)d_ws;
  float* bias2 = wsf + WS_BIAS2;
  float* emean = wsf + WS_EMEAN;
  float* Sv    = wsf + WS_S;
  unsigned short* Wst = (unsigned short*)(wsf + WS_WST);  // peW | pdW
  unsigned short* peW = Wst;
  unsigned short* pdW = Wst + 196608;
  float* peB   = wsf + PEB_F;
  unsigned short* BIG = (unsigned short*)(wsf + WS_BIG);
  unsigned short* Zs  = (unsigned short*)(wsf + WS_BIG);  // bf16 Z overlay
  float* out   = (float*)d_out;
  unsigned short* X    = (unsigned short*)(out + OUT_XSCR);   // bf16 residual
  unsigned short* WSTK = (unsigned short*)(out + OUT_WSTK);   // converted weights

  meta_kernel<<<1, 64, 0, stream>>>(tl, mi);
  // convert all layer weights up front (4 passes)
  for (int p = 0; p < 4; p++) {
    const float* const* q = P + (p >> 1) * 12;
    const int i = p & 1;
    w2bf4_kernel<<<WPASS / 1024, 256, 0, stream>>>(
        q[0] + (size_t)i * 3 * D_ * D_, q[2] + (size_t)i * D_ * D_,
        q[6] + (size_t)i * F_ * D_, q[8] + (size_t)i * D_ * F_,
        WSTK + (size_t)p * WPASS);
  }
  pepd_stage<<<385, 256, 0, stream>>>(P[24], P[25], P[26], peW, pdW, peB);
  gather_kernel<<<NP_ * L_, 192, 0, stream>>>(emb, am, mi, X, bias2);
  emean_kernel<<<NP_, 256, 0, stream>>>(X, emean);
  zerotail_kernel<<<NP_ * L_, 256, 0, stream>>>(mi, BIG);

  const int RT2 = NP_ * 64 / 256;   // 128 row tiles (worst case)
  for (int s = 0; s < 2; s++) {
    const float* const* q = P + s * 12;
    for (int i = 0; i < 2; i++) {
      const unsigned short* WP = WSTK + (size_t)(s * 2 + i) * WPASS;
      // QKV: X -> BIG [rows, 2304]
      gemm_mfma<0, false><<<RT2 * 9, 512, 0, stream>>>(
          X, D_, D_, WP, D_, q[1] + i * 3 * D_, BIG, 3 * D_, 9, mi);
      attn_kernel<<<dim3(L_ * H_, 4), 512, 0, stream>>>(BIG, bias2, mi);
      // out-proj: O (Q cols of BIG, lda=2304) -> += X
      gemm_mfma<0, true><<<RT2 * 3, 512, 0, stream>>>(
          BIG, 3 * D_, D_, WP + WSEG0, D_, q[3] + i * D_, X, D_, 3, mi);
      ln_kernel<<<NP_ * L_, 256, 0, stream>>>(X, q[4] + i * D_, q[5] + i * D_, mi);
      // FFN1: X -> hidden BIG [rows, 2048] (relu)
      gemm_mfma<1, false><<<RT2 * 8, 512, 0, stream>>>(
          X, D_, D_, WP + WSEG0 + WSEG1, D_, q[7] + i * F_, BIG, F_, 8, mi);
      // FFN2: hidden -> += X
      gemm_mfma<0, true><<<RT2 * 3, 512, 0, stream>>>(
          BIG, F_, F_, WP + WSEG0 + WSEG1 + WSEG2, F_, q[9] + i * D_, X, D_, 3, mi);
      ln_kernel<<<NP_ * L_, 256, 0, stream>>>(X, q[10] + i * D_, q[11] + i * D_, mi);
    }
    if (s == 0) {
      // z = tanh(h @ pe_w^T + pe_b) -> Zs bf16 [rows][256] (cols 100..255 = 0)
      gemm_mfma<2, false><<<RT2 * 1, 512, 0, stream>>>(
          X, D_, D_, peW, D_, peB, Zs, 256, 1, mi);
      // zd = tanh(z @ pd_w^T + pd_b) -> X bf16 (decoder input)
      gemm_mfma<2, false><<<RT2 * 3, 512, 0, stream>>>(
          Zs, 256, 256, pdW, 256, P[27], X, D_, 3, mi);
    }
  }

  score_kernel<<<NP_, 256, 0, stream>>>(X, emean, Sv);
  finalize_kernel<<<1, 256, 0, stream>>>(Sv, mi, out);
  maskout_kernel<<<128, 256, 0, stream>>>(am, mi, out);
  newemb_kernel<<<B_ * T_ * L_, 192, 0, stream>>>(emb, mi, out);
}